// Round 11
// baseline (484.399 us; speedup 1.0000x reference)
//
#include <hip/hip_runtime.h>
#include <hip/hip_cooperative_groups.h>

namespace cg = cooperative_groups;

#define FN 32
#define FE 16
#define HID 64
#define HEADS 4
#define CHC 64
// H*C = 256

typedef float f32x4 __attribute__((ext_vector_type(4)));

__device__ __forceinline__ float bf2f(unsigned short u) {
  unsigned int x = ((unsigned int)u) << 16;
  return __builtin_bit_cast(float, x);
}
__device__ __forceinline__ unsigned short f2bf(float f) {
  unsigned int x = __builtin_bit_cast(unsigned int, f);
  unsigned int r = (x + 0x7fff + ((x >> 16) & 1)) >> 16;   // RNE
  return (unsigned short)r;
}
__device__ __forceinline__ unsigned int pack2bf(float a, float b) {
  return (unsigned int)f2bf(a) | ((unsigned int)f2bf(b) << 16);
}

// ================= ONE cooperative preprocessing kernel =================
// P0 zero deg + fold-vectors | P1 degree atomics | P2 per-chunk scan |
// P3 apply offsets (+cnt=rowptr copy, rowptr[n]) | P4 CSR fill + edge-aeg |
// P5 self-loop aeg (segment mean).
__global__ __launch_bounds__(256) void k_prep(
    const int* __restrict__ eidx, const float* __restrict__ eattr,
    const float* __restrict__ we, const float* __restrict__ be,
    const float* __restrict__ lin1, const float* __restrict__ line1,
    const float* __restrict__ as1, const float* __restrict__ ad1,
    const float* __restrict__ ae1,
    const float* __restrict__ lin2, const float* __restrict__ line2,
    const float* __restrict__ as2, const float* __restrict__ ad2,
    const float* __restrict__ ae2,
    float* __restrict__ vS, float* __restrict__ vD, float* __restrict__ vE,
    int* __restrict__ deg, int* __restrict__ cnt, int* __restrict__ rowptr,
    int* __restrict__ bsum, int* __restrict__ eid, int* __restrict__ srcs,
    float* __restrict__ aeg1, float* __restrict__ aeg2, int n, int E)
{
  cg::grid_group grid = cg::this_grid();
  int t = threadIdx.x, b = blockIdx.x;
  int gsz = gridDim.x * 256;
  int gtid = b * 256 + t;
  const int* srcA = eidx;
  const int* dstA = eidx + E;

  // ---- P0: zero deg; blocks 0..5 also compute vS/vD/vE ----
  for (int i = gtid; i < n; i += gsz) deg[i] = 0;
  if (b < 6) {
    int l = b / 3, kind = b % 3;
    const float* lin = (kind == 2) ? (l ? line2 : line1) : (l ? lin2 : lin1);
    const float* att = (kind == 0) ? (l ? as2 : as1)
                     : (kind == 1) ? (l ? ad2 : ad1) : (l ? ae2 : ae1);
    float* out = ((kind == 0) ? vS : (kind == 1) ? vD : vE) + l * 256;
    int c = t >> 2, hd = t & 3;
    float acc = 0.f;
    for (int cc = 0; cc < CHC; cc++)
      acc += lin[c * (HEADS * CHC) + hd * CHC + cc] * att[hd * CHC + cc];
    out[c * 4 + hd] = acc;
  }
  grid.sync();

  // ---- P1: degree count ----
  for (int e = gtid; e < E; e += gsz) atomicAdd(&deg[dstA[e]], 1);
  grid.sync();

  // ---- P2: per-256-chunk exclusive scan ----
  int nbs = (n + 255) / 256;
  __shared__ int wsum[4];
  if (b < nbs) {
    int lane = t & 63, wv = t >> 6;
    int i = b * 256 + t;
    int val = (i < n) ? deg[i] : 0;
    int sc = val;
    #pragma unroll
    for (int off = 1; off < 64; off <<= 1) {
      int u = __shfl_up(sc, off);
      if (lane >= off) sc += u;
    }
    if (lane == 63) wsum[wv] = sc;
    __syncthreads();
    int woff = 0;
    #pragma unroll
    for (int k = 0; k < 4; k++) woff += (k < wv) ? wsum[k] : 0;
    if (i < n) rowptr[i] = woff + sc - val;
    if (t == 0) {
      int tot = wsum[0] + wsum[1] + wsum[2] + wsum[3];
      bsum[b] = tot;
    }
  }
  grid.sync();

  // ---- P3: apply block offsets; copy rowptr -> cnt; rowptr[n] ----
  if (b < nbs) {
    int off = 0;
    for (int j = 0; j < b; j++) off += bsum[j];
    int i = b * 256 + t;
    if (i < n) {
      int rv = rowptr[i] + off;
      rowptr[i] = rv;
      cnt[i] = rv;
    }
  }
  if (b == 0 && t == 0) {
    int tot = 0;
    for (int j = 0; j < nbs; j++) tot += bsum[j];
    rowptr[n] = tot;
  }
  grid.sync();

  // ---- P4: CSR fill + edge a_edge (fused; no perm array) ----
  __shared__ float4 we_t4[HID][4];   // we^T
  __shared__ float4 vE_s[2][HID];
  __shared__ float  be_s[HID];
  for (int i = t; i < FE * HID; i += 256) {
    int k = i >> 6, c = i & 63;
    ((float*)we_t4)[c * 16 + k] = we[i];
  }
  for (int i = t; i < 512; i += 256) ((float*)vE_s)[i] = vE[i];
  if (t < HID) be_s[t] = be[t];
  __syncthreads();
  for (int e = gtid; e < E; e += gsz) {
    int d = dstA[e];
    int pos = atomicAdd(&cnt[d], 1);
    eid[pos] = e;
    srcs[pos] = srcA[e];
    const float4* er = (const float4*)(eattr + (size_t)e * FE);
    float4 A = er[0], B = er[1], C4 = er[2], D = er[3];
    float ta[FE] = {A.x, A.y, A.z, A.w, B.x, B.y, B.z, B.w,
                    C4.x, C4.y, C4.z, C4.w, D.x, D.y, D.z, D.w};
    float4 acc1 = make_float4(0.f, 0.f, 0.f, 0.f);
    float4 acc2 = make_float4(0.f, 0.f, 0.f, 0.f);
    #pragma unroll 4
    for (int c = 0; c < HID; c++) {
      float4 w0 = we_t4[c][0], w1 = we_t4[c][1], w2 = we_t4[c][2], w3 = we_t4[c][3];
      float ea = be_s[c];
      ea += ta[0] * w0.x + ta[1] * w0.y + ta[2] * w0.z + ta[3] * w0.w;
      ea += ta[4] * w1.x + ta[5] * w1.y + ta[6] * w1.z + ta[7] * w1.w;
      ea += ta[8] * w2.x + ta[9] * w2.y + ta[10] * w2.z + ta[11] * w2.w;
      ea += ta[12] * w3.x + ta[13] * w3.y + ta[14] * w3.z + ta[15] * w3.w;
      ea = fmaxf(ea, 0.f);
      float4 u1 = vE_s[0][c], u2 = vE_s[1][c];
      acc1.x += ea * u1.x; acc1.y += ea * u1.y; acc1.z += ea * u1.z; acc1.w += ea * u1.w;
      acc2.x += ea * u2.x; acc2.y += ea * u2.y; acc2.z += ea * u2.z; acc2.w += ea * u2.w;
    }
    *(float4*)(aeg1 + (size_t)pos * 4) = acc1;
    *(float4*)(aeg2 + (size_t)pos * 4) = acc2;
  }
  grid.sync();

  // ---- P5: self-loop aeg = segment mean ----
  for (int w = gtid; w < n * 8; w += gsz) {
    int v = w >> 3;
    int ent = w & 7, h = ent & 3;
    const float* sp = (ent < 4) ? aeg1 : aeg2;
    int r0 = rowptr[v], r1 = rowptr[v + 1];
    float s = 0.f;
    for (int j = r0; j < r1; j++) s += sp[(size_t)j * 4 + h];
    float m = s / fmaxf((float)(r1 - r0), 1.f);
    if (ent < 4) aeg1[((size_t)E + v) * 4 + h] = m;
    else         aeg2[((size_t)E + v) * 4 + h] = m;
  }
}

// Fused layer-1 front-end: x1 = relu(x@wn+bn) (LDS only) + att dots +
// h(bf16) = x1 @ lin. 16 nodes/block.
__global__ __launch_bounds__(256) void k_hx1(const float* __restrict__ x,
    const float* __restrict__ wn, const float* __restrict__ bn,
    const float* __restrict__ vS, const float* __restrict__ vD,
    const float* __restrict__ lin, unsigned short* __restrict__ h_bf,
    float* __restrict__ ssrc, float* __restrict__ sdst, int n)
{
  int t = threadIdx.x, wv = t >> 6, lane = t & 63;
  int v0 = blockIdx.x * 16;
  __shared__ float xin_s[16][FN];
  __shared__ float xs[16][HID];
  if (t < 128) {
    int node = t >> 3, c4 = (t & 7) * 4;
    int vv = v0 + node;
    float4 val = make_float4(0.f, 0.f, 0.f, 0.f);
    if (vv < n) val = *(const float4*)(x + (size_t)vv * FN + c4);
    *(float4*)&xin_s[node][c4] = val;
  }
  __syncthreads();
  {
    int nd = t >> 4, cg_ = t & 15;
    int vv = v0 + nd;
    const float4* wn4 = (const float4*)wn;
    float4 a = ((const float4*)bn)[cg_];
    #pragma unroll 8
    for (int k = 0; k < FN; k++) {
      float xv = xin_s[nd][k];
      float4 w = wn4[k * 16 + cg_];
      a.x += xv * w.x; a.y += xv * w.y; a.z += xv * w.z; a.w += xv * w.w;
    }
    a.x = fmaxf(a.x, 0.f); a.y = fmaxf(a.y, 0.f);
    a.z = fmaxf(a.z, 0.f); a.w = fmaxf(a.w, 0.f);
    *(float4*)&xs[nd][cg_ * 4] = a;
    const float4* vS4 = (const float4*)vS;
    const float4* vD4 = (const float4*)vD;
    int c0 = cg_ * 4;
    float4 vs0 = vS4[c0], vs1 = vS4[c0 + 1], vs2 = vS4[c0 + 2], vs3 = vS4[c0 + 3];
    float4 vd0 = vD4[c0], vd1 = vD4[c0 + 1], vd2 = vD4[c0 + 2], vd3 = vD4[c0 + 3];
    float pS[4], pD[4];
    pS[0] = a.x * vs0.x + a.y * vs1.x + a.z * vs2.x + a.w * vs3.x;
    pS[1] = a.x * vs0.y + a.y * vs1.y + a.z * vs2.y + a.w * vs3.y;
    pS[2] = a.x * vs0.z + a.y * vs1.z + a.z * vs2.z + a.w * vs3.z;
    pS[3] = a.x * vs0.w + a.y * vs1.w + a.z * vs2.w + a.w * vs3.w;
    pD[0] = a.x * vd0.x + a.y * vd1.x + a.z * vd2.x + a.w * vd3.x;
    pD[1] = a.x * vd0.y + a.y * vd1.y + a.z * vd2.y + a.w * vd3.y;
    pD[2] = a.x * vd0.z + a.y * vd1.z + a.z * vd2.z + a.w * vd3.z;
    pD[3] = a.x * vd0.w + a.y * vd1.w + a.z * vd2.w + a.w * vd3.w;
    #pragma unroll
    for (int off = 1; off < 16; off <<= 1) {
      #pragma unroll
      for (int h = 0; h < 4; h++) {
        pS[h] += __shfl_xor(pS[h], off);
        pD[h] += __shfl_xor(pD[h], off);
      }
    }
    if (cg_ == 0 && vv < n) {
      *(float4*)(ssrc + (size_t)vv * 4) = make_float4(pS[0], pS[1], pS[2], pS[3]);
      *(float4*)(sdst + (size_t)vv * 4) = make_float4(pD[0], pD[1], pD[2], pD[3]);
    }
  }
  __syncthreads();
  float acc[4][4];
  #pragma unroll
  for (int i = 0; i < 4; i++)
    #pragma unroll
    for (int j = 0; j < 4; j++) acc[i][j] = 0.f;
  const float4* lin4 = (const float4*)lin;
  int nd0 = wv * 4;
  #pragma unroll 4
  for (int kb = 0; kb < 16; kb++) {
    float4 xv[4];
    #pragma unroll
    for (int i = 0; i < 4; i++) xv[i] = *(const float4*)&xs[nd0 + i][kb * 4];
    float4 lv0 = lin4[(kb * 4 + 0) * 64 + lane];
    float4 lv1 = lin4[(kb * 4 + 1) * 64 + lane];
    float4 lv2 = lin4[(kb * 4 + 2) * 64 + lane];
    float4 lv3 = lin4[(kb * 4 + 3) * 64 + lane];
    #pragma unroll
    for (int i = 0; i < 4; i++) {
      acc[i][0] += xv[i].x * lv0.x + xv[i].y * lv1.x + xv[i].z * lv2.x + xv[i].w * lv3.x;
      acc[i][1] += xv[i].x * lv0.y + xv[i].y * lv1.y + xv[i].z * lv2.y + xv[i].w * lv3.y;
      acc[i][2] += xv[i].x * lv0.z + xv[i].y * lv1.z + xv[i].z * lv2.z + xv[i].w * lv3.z;
      acc[i][3] += xv[i].x * lv0.w + xv[i].y * lv1.w + xv[i].z * lv2.w + xv[i].w * lv3.w;
    }
  }
  #pragma unroll
  for (int i = 0; i < 4; i++) {
    int v = v0 + nd0 + i;
    if (v < n) {
      uint2 u;
      u.x = pack2bf(acc[i][0], acc[i][1]);
      u.y = pack2bf(acc[i][2], acc[i][3]);
      *(uint2*)(h_bf + (size_t)v * 256 + lane * 4) = u;
    }
  }
}

// h(bf16) = x @ lin [n,256]. 16 nodes/block; thread = 4 nodes x 4 channels.
__global__ __launch_bounds__(256) void k_h(const float* __restrict__ xin,
    const float* __restrict__ lin, unsigned short* __restrict__ h_bf, int n)
{
  int t = threadIdx.x, wv = t >> 6, lane = t & 63;
  int v0 = blockIdx.x * 16;
  __shared__ float xs[16][HID];
  {
    int node = t >> 4, ch4 = (t & 15) * 4;
    int vv = v0 + node;
    float4 val = make_float4(0.f, 0.f, 0.f, 0.f);
    if (vv < n) val = *(const float4*)(xin + (size_t)vv * HID + ch4);
    *(float4*)&xs[node][ch4] = val;
  }
  __syncthreads();
  float acc[4][4];
  #pragma unroll
  for (int i = 0; i < 4; i++)
    #pragma unroll
    for (int j = 0; j < 4; j++) acc[i][j] = 0.f;
  const float4* lin4 = (const float4*)lin;
  int nd0 = wv * 4;
  #pragma unroll 4
  for (int kb = 0; kb < 16; kb++) {
    float4 xv[4];
    #pragma unroll
    for (int i = 0; i < 4; i++) xv[i] = *(const float4*)&xs[nd0 + i][kb * 4];
    float4 lv0 = lin4[(kb * 4 + 0) * 64 + lane];
    float4 lv1 = lin4[(kb * 4 + 1) * 64 + lane];
    float4 lv2 = lin4[(kb * 4 + 2) * 64 + lane];
    float4 lv3 = lin4[(kb * 4 + 3) * 64 + lane];
    #pragma unroll
    for (int i = 0; i < 4; i++) {
      acc[i][0] += xv[i].x * lv0.x + xv[i].y * lv1.x + xv[i].z * lv2.x + xv[i].w * lv3.x;
      acc[i][1] += xv[i].x * lv0.y + xv[i].y * lv1.y + xv[i].z * lv2.y + xv[i].w * lv3.y;
      acc[i][2] += xv[i].x * lv0.z + xv[i].y * lv1.z + xv[i].z * lv2.z + xv[i].w * lv3.z;
      acc[i][3] += xv[i].x * lv0.w + xv[i].y * lv1.w + xv[i].z * lv2.w + xv[i].w * lv3.w;
    }
  }
  #pragma unroll
  for (int i = 0; i < 4; i++) {
    int v = v0 + nd0 + i;
    if (v < n) {
      uint2 u;
      u.x = pack2bf(acc[i][0], acc[i][1]);
      u.y = pack2bf(acc[i][2], acc[i][3]);
      *(uint2*)(h_bf + (size_t)v * 256 + lane * 4) = u;
    }
  }
}

// Fused per-node: softmax + alpha + aggregation + head-mean + bias + leaky +
// LayerNorm (+ optional fused next-layer att dots). WAVE per node (best-known
// R6 structure: shfl src broadcast, als[4][64][4], 4-deep gather).
template<bool DOTS>
__global__ __launch_bounds__(256) void k_node(
    const unsigned short* __restrict__ h_bf, const float* __restrict__ ssrc,
    const float* __restrict__ sdst, const float* __restrict__ aegc,
    const int* __restrict__ rowptr, const int* __restrict__ eidArr,
    const int* __restrict__ srcs, const float* __restrict__ bias,
    const float* __restrict__ gamma, const float* __restrict__ beta,
    const float* __restrict__ vS2, const float* __restrict__ vD2,
    float* __restrict__ alpha_out, float* __restrict__ xout,
    float* __restrict__ ssrc_o, float* __restrict__ sdst_o, int n, int E)
{
  __shared__ float als[4][64][4];   // per-wave alpha exchange (conflict-free)
  int t = threadIdx.x; int wv = t >> 6, lane = t & 63;
  int v = blockIdx.x * 4 + wv;
  if (v >= n) return;
  int r0 = rowptr[v], r1 = rowptr[v + 1];
  int deg = r1 - r0, ne = deg + 1;      // + self loop (edge id E+v, src v)
  int coff = lane * 4;                  // aggregation: 4 channels per lane
  int hh = lane >> 4;                   // head owning those channels
  float acc0 = 0.f, acc1 = 0.f, acc2 = 0.f, acc3 = 0.f;
  const float4* aeg4 = (const float4*)aegc;
  const float4* ss4p = (const float4*)ssrc;
  float4 sd4 = ((const float4*)sdst)[v];

  if (ne <= 64) {
    int s = v, eo = E + v;
    if (lane < deg) { s = srcs[r0 + lane]; eo = eidArr[r0 + lane]; }
    bool valid = (lane < ne);
    float a0 = -INFINITY, a1 = -INFINITY, a2 = -INFINITY, a3 = -INFINITY;
    if (valid) {
      float4 ae4 = aeg4[(lane < deg) ? (r0 + lane) : (E + v)];
      float4 ss4 = ss4p[s];
      a0 = ss4.x + sd4.x + ae4.x; a0 = (a0 > 0.f) ? a0 : 0.2f * a0;
      a1 = ss4.y + sd4.y + ae4.y; a1 = (a1 > 0.f) ? a1 : 0.2f * a1;
      a2 = ss4.z + sd4.z + ae4.z; a2 = (a2 > 0.f) ? a2 : 0.2f * a2;
      a3 = ss4.w + sd4.w + ae4.w; a3 = (a3 > 0.f) ? a3 : 0.2f * a3;
    }
    float m0, m1, m2, m3;
    {
      bool hi0 = lane & 1;
      float k0 = hi0 ? a2 : a0, s0 = hi0 ? a0 : a2;
      float k1 = hi0 ? a3 : a1, s1 = hi0 ? a1 : a3;
      float q0 = fmaxf(k0, __shfl_xor(s0, 1));
      float q1 = fmaxf(k1, __shfl_xor(s1, 1));
      bool hi1 = lane & 2;
      float k2 = hi1 ? q1 : q0, s2 = hi1 ? q0 : q1;
      float r = fmaxf(k2, __shfl_xor(s2, 2));
      r = fmaxf(r, __shfl_xor(r, 4));
      r = fmaxf(r, __shfl_xor(r, 8));
      r = fmaxf(r, __shfl_xor(r, 16));
      r = fmaxf(r, __shfl_xor(r, 32));
      m0 = __shfl(r, 0); m1 = __shfl(r, 2); m2 = __shfl(r, 1); m3 = __shfl(r, 3);
    }
    float e0 = __expf(a0 - m0), e1 = __expf(a1 - m1);
    float e2 = __expf(a2 - m2), e3 = __expf(a3 - m3);
    float d0, d1, d2, d3;
    {
      bool hi0 = lane & 1;
      float k0 = hi0 ? e2 : e0, s0 = hi0 ? e0 : e2;
      float k1 = hi0 ? e3 : e1, s1 = hi0 ? e1 : e3;
      float q0 = k0 + __shfl_xor(s0, 1);
      float q1 = k1 + __shfl_xor(s1, 1);
      bool hi1 = lane & 2;
      float k2 = hi1 ? q1 : q0, s2 = hi1 ? q0 : q1;
      float r = k2 + __shfl_xor(s2, 2);
      r += __shfl_xor(r, 4);
      r += __shfl_xor(r, 8);
      r += __shfl_xor(r, 16);
      r += __shfl_xor(r, 32);
      d0 = __shfl(r, 0); d1 = __shfl(r, 2); d2 = __shfl(r, 1); d3 = __shfl(r, 3);
    }
    float4 alf = make_float4(e0 / d0, e1 / d1, e2 / d2, e3 / d3);
    if (valid) {
      f32x4 alv = {alf.x, alf.y, alf.z, alf.w};
      __builtin_nontemporal_store(alv, (f32x4*)alpha_out + eo);
    }
    *(float4*)als[wv][lane] = alf;
    __builtin_amdgcn_wave_barrier();
    __builtin_amdgcn_sched_barrier(0);
    int jj = 0;
    for (; jj + 3 < ne; jj += 4) {
      int s0 = __shfl(s, jj), s1 = __shfl(s, jj + 1);
      int s2 = __shfl(s, jj + 2), s3 = __shfl(s, jj + 3);
      float al0 = als[wv][jj][hh],     al1 = als[wv][jj + 1][hh];
      float al2 = als[wv][jj + 2][hh], al3 = als[wv][jj + 3][hh];
      uint2 u0 = *(const uint2*)(h_bf + (size_t)s0 * 256 + coff);
      uint2 u1 = *(const uint2*)(h_bf + (size_t)s1 * 256 + coff);
      uint2 u2 = *(const uint2*)(h_bf + (size_t)s2 * 256 + coff);
      uint2 u3 = *(const uint2*)(h_bf + (size_t)s3 * 256 + coff);
      acc0 += al0 * bf2f((unsigned short)(u0.x & 0xffff))
            + al1 * bf2f((unsigned short)(u1.x & 0xffff))
            + al2 * bf2f((unsigned short)(u2.x & 0xffff))
            + al3 * bf2f((unsigned short)(u3.x & 0xffff));
      acc1 += al0 * bf2f((unsigned short)(u0.x >> 16))
            + al1 * bf2f((unsigned short)(u1.x >> 16))
            + al2 * bf2f((unsigned short)(u2.x >> 16))
            + al3 * bf2f((unsigned short)(u3.x >> 16));
      acc2 += al0 * bf2f((unsigned short)(u0.y & 0xffff))
            + al1 * bf2f((unsigned short)(u1.y & 0xffff))
            + al2 * bf2f((unsigned short)(u2.y & 0xffff))
            + al3 * bf2f((unsigned short)(u3.y & 0xffff));
      acc3 += al0 * bf2f((unsigned short)(u0.y >> 16))
            + al1 * bf2f((unsigned short)(u1.y >> 16))
            + al2 * bf2f((unsigned short)(u2.y >> 16))
            + al3 * bf2f((unsigned short)(u3.y >> 16));
    }
    for (; jj < ne; jj++) {
      int s0 = __shfl(s, jj);
      float al0 = als[wv][jj][hh];
      uint2 u0 = *(const uint2*)(h_bf + (size_t)s0 * 256 + coff);
      acc0 += al0 * bf2f((unsigned short)(u0.x & 0xffff));
      acc1 += al0 * bf2f((unsigned short)(u0.x >> 16));
      acc2 += al0 * bf2f((unsigned short)(u0.y & 0xffff));
      acc3 += al0 * bf2f((unsigned short)(u0.y >> 16));
    }
  } else {
    // ---- chunked two-pass fallback (deg > 63, rare) ----
    int j4 = lane >> 2, hb = lane & 3;
    float sd = sdst[v * 4 + hb];
    float m = -INFINITY;
    for (int jb = 0; jb < ne; jb += 16) {
      int jc = jb + j4;
      if (jc < ne) {
        int s2 = (jc < deg) ? srcs[r0 + jc] : v;
        float ae = (jc < deg) ? aegc[(size_t)(r0 + jc) * 4 + hb]
                              : aegc[((size_t)E + v) * 4 + hb];
        float a = ssrc[s2 * 4 + hb] + sd + ae;
        a = (a > 0.f) ? a : 0.2f * a;
        m = fmaxf(m, a);
      }
    }
    m = fmaxf(m, __shfl_xor(m, 4));
    m = fmaxf(m, __shfl_xor(m, 8));
    m = fmaxf(m, __shfl_xor(m, 16));
    m = fmaxf(m, __shfl_xor(m, 32));
    float den = 0.f;
    for (int jb = 0; jb < ne; jb += 16) {
      int jc = jb + j4;
      if (jc < ne) {
        int s2 = (jc < deg) ? srcs[r0 + jc] : v;
        float ae = (jc < deg) ? aegc[(size_t)(r0 + jc) * 4 + hb]
                              : aegc[((size_t)E + v) * 4 + hb];
        float a = ssrc[s2 * 4 + hb] + sd + ae;
        a = (a > 0.f) ? a : 0.2f * a;
        den += __expf(a - m);
      }
    }
    den += __shfl_xor(den, 4);
    den += __shfl_xor(den, 8);
    den += __shfl_xor(den, 16);
    den += __shfl_xor(den, 32);
    float rden = 1.f / den;
    for (int jb = 0; jb < ne; jb += 16) {
      int jc = jb + j4;
      if (jc < ne) {
        int s2 = (jc < deg) ? srcs[r0 + jc] : v;
        int eo = (jc < deg) ? eidArr[r0 + jc] : E + v;
        float ae = (jc < deg) ? aegc[(size_t)(r0 + jc) * 4 + hb]
                              : aegc[((size_t)E + v) * 4 + hb];
        float a = ssrc[s2 * 4 + hb] + sd + ae;
        a = (a > 0.f) ? a : 0.2f * a;
        alpha_out[(size_t)eo * 4 + hb] = __expf(a - m) * rden;
      }
    }
    float sdh = __shfl(sd, hh);
    float mh  = __shfl(m, hh);
    float rdh = __shfl(rden, hh);
    for (int jc = 0; jc < ne; jc++) {
      int s0 = (jc < deg) ? srcs[r0 + jc] : v;
      size_t ap = (jc < deg) ? (size_t)(r0 + jc) : (size_t)E + v;
      float a = ssrc[s0 * 4 + hh] + sdh + aegc[ap * 4 + hh];
      a = (a > 0.f) ? a : 0.2f * a;
      float al = __expf(a - mh) * rdh;
      uint2 u = *(const uint2*)(h_bf + (size_t)s0 * 256 + coff);
      acc0 += al * bf2f((unsigned short)(u.x & 0xffff));
      acc1 += al * bf2f((unsigned short)(u.x >> 16));
      acc2 += al * bf2f((unsigned short)(u.y & 0xffff));
      acc3 += al * bf2f((unsigned short)(u.y >> 16));
    }
  }

  // ---- head reduce: lanes {L, L+16, L+32, L+48} hold heads 0..3 ----
  acc0 += __shfl_xor(acc0, 16); acc0 += __shfl_xor(acc0, 32);
  acc1 += __shfl_xor(acc1, 16); acc1 += __shfl_xor(acc1, 32);
  acc2 += __shfl_xor(acc2, 16); acc2 += __shfl_xor(acc2, 32);
  acc3 += __shfl_xor(acc3, 16); acc3 += __shfl_xor(acc3, 32);

  // ---- epilogue: bias + leaky(0.01) + LayerNorm(64); all lanes hold copy ----
  int c16 = lane & 15;
  float4 b4 = ((const float4*)bias)[c16];
  float v0 = acc0 * 0.25f + b4.x;
  float v1 = acc1 * 0.25f + b4.y;
  float v2 = acc2 * 0.25f + b4.z;
  float v3 = acc3 * 0.25f + b4.w;
  v0 = (v0 > 0.f) ? v0 : 0.01f * v0;
  v1 = (v1 > 0.f) ? v1 : 0.01f * v1;
  v2 = (v2 > 0.f) ? v2 : 0.01f * v2;
  v3 = (v3 > 0.f) ? v3 : 0.01f * v3;
  float mu = v0 + v1 + v2 + v3;
  mu += __shfl_xor(mu, 1); mu += __shfl_xor(mu, 2);
  mu += __shfl_xor(mu, 4); mu += __shfl_xor(mu, 8);
  mu *= (1.f / 64.f);
  float d0 = v0 - mu, d1 = v1 - mu, d2 = v2 - mu, d3 = v3 - mu;
  float var = d0 * d0 + d1 * d1 + d2 * d2 + d3 * d3;
  var += __shfl_xor(var, 1); var += __shfl_xor(var, 2);
  var += __shfl_xor(var, 4); var += __shfl_xor(var, 8);
  var *= (1.f / 64.f);
  float rstd = rsqrtf(var + 1e-5f);
  float4 g4 = ((const float4*)gamma)[c16];
  float4 be4 = ((const float4*)beta)[c16];
  float y0 = d0 * rstd * g4.x + be4.x;
  float y1 = d1 * rstd * g4.y + be4.y;
  float y2 = d2 * rstd * g4.z + be4.z;
  float y3 = d3 * rstd * g4.w + be4.w;
  if (lane < 16) {
    float4 y = make_float4(y0, y1, y2, y3);
    *(float4*)(xout + (size_t)v * HID + lane * 4) = y;
  }
  if constexpr (DOTS) {
    // next-layer att dots: p_h = y . vS2[:,h]; 16-lane reduce = ONE full copy
    int c0 = c16 * 4;
    float4 vs0 = ((const float4*)vS2)[c0],     vs1 = ((const float4*)vS2)[c0 + 1];
    float4 vs2 = ((const float4*)vS2)[c0 + 2], vs3 = ((const float4*)vS2)[c0 + 3];
    float4 vd0 = ((const float4*)vD2)[c0],     vd1 = ((const float4*)vD2)[c0 + 1];
    float4 vd2 = ((const float4*)vD2)[c0 + 2], vd3 = ((const float4*)vD2)[c0 + 3];
    float pS[4], pD[4];
    pS[0] = y0 * vs0.x + y1 * vs1.x + y2 * vs2.x + y3 * vs3.x;
    pS[1] = y0 * vs0.y + y1 * vs1.y + y2 * vs2.y + y3 * vs3.y;
    pS[2] = y0 * vs0.z + y1 * vs1.z + y2 * vs2.z + y3 * vs3.z;
    pS[3] = y0 * vs0.w + y1 * vs1.w + y2 * vs2.w + y3 * vs3.w;
    pD[0] = y0 * vd0.x + y1 * vd1.x + y2 * vd2.x + y3 * vd3.x;
    pD[1] = y0 * vd0.y + y1 * vd1.y + y2 * vd2.y + y3 * vd3.y;
    pD[2] = y0 * vd0.z + y1 * vd1.z + y2 * vd2.z + y3 * vd3.z;
    pD[3] = y0 * vd0.w + y1 * vd1.w + y2 * vd2.w + y3 * vd3.w;
    #pragma unroll
    for (int off = 1; off < 16; off <<= 1) {
      #pragma unroll
      for (int h = 0; h < 4; h++) {
        pS[h] += __shfl_xor(pS[h], off);
        pD[h] += __shfl_xor(pD[h], off);
      }
    }
    if (lane == 0) {
      *(float4*)(ssrc_o + (size_t)v * 4) = make_float4(pS[0], pS[1], pS[2], pS[3]);
      *(float4*)(sdst_o + (size_t)v * 4) = make_float4(pD[0], pD[1], pD[2], pD[3]);
    }
  }
}

extern "C" void kernel_launch(void* const* d_in, const int* in_sizes, int n_in,
                              void* d_out, int out_size, void* d_ws, size_t ws_size,
                              hipStream_t stream)
{
  const float* x     = (const float*)d_in[0];
  const int*   eidx  = (const int*)d_in[1];
  const float* eattr = (const float*)d_in[2];
  const float* wn    = (const float*)d_in[3];
  const float* bn    = (const float*)d_in[4];
  const float* we    = (const float*)d_in[5];
  const float* be    = (const float*)d_in[6];
  const float* lin1  = (const float*)d_in[7];
  const float* line1 = (const float*)d_in[8];
  const float* as1   = (const float*)d_in[9];
  const float* ad1   = (const float*)d_in[10];
  const float* ae1   = (const float*)d_in[11];
  const float* b1    = (const float*)d_in[12];
  const float* g1    = (const float*)d_in[13];
  const float* bt1   = (const float*)d_in[14];
  const float* lin2  = (const float*)d_in[15];
  const float* line2 = (const float*)d_in[16];
  const float* as2   = (const float*)d_in[17];
  const float* ad2   = (const float*)d_in[18];
  const float* ae2   = (const float*)d_in[19];
  const float* b2    = (const float*)d_in[20];
  const float* g2    = (const float*)d_in[21];
  const float* bt2   = (const float*)d_in[22];

  int n = in_sizes[0] / FN;
  int E = in_sizes[1] / 2;

  float* out_h2 = (float*)d_out;
  float* alpha1 = out_h2 + (size_t)n * HID;
  float* alpha2 = alpha1 + (size_t)(E + n) * 4;

  char* ws = (char*)d_ws;
  size_t off = 0;
  auto alloc = [&](size_t bytes) -> char* {
    char* p = ws + off;
    off += (bytes + 255) & ~(size_t)255;
    return p;
  };
  unsigned short* h_bf = (unsigned short*)alloc((size_t)n * 256 * 2);
  float* h1      = (float*)alloc((size_t)n * HID * 4);
  float* aeg1c   = (float*)alloc((size_t)(E + n) * 4 * 4);
  float* aeg2c   = (float*)alloc((size_t)(E + n) * 4 * 4);
  float* ssrc1   = (float*)alloc((size_t)n * 4 * 4);
  float* sdst1   = (float*)alloc((size_t)n * 4 * 4);
  float* ssrc2   = (float*)alloc((size_t)n * 4 * 4);
  float* sdst2   = (float*)alloc((size_t)n * 4 * 4);
  float* vS      = (float*)alloc(512 * 4);
  float* vD      = (float*)alloc(512 * 4);
  float* vE      = (float*)alloc(512 * 4);
  int*   deg     = (int*)alloc((size_t)n * 4);
  int*   cnt     = (int*)alloc((size_t)n * 4);
  int*   rowptr  = (int*)alloc((size_t)(n + 1) * 4);
  int*   eid     = (int*)alloc((size_t)E * 4);
  int*   srcs    = (int*)alloc((size_t)E * 4);
  int*   bsum    = (int*)alloc(1024 * 4);

  // single cooperative preprocessing kernel (512 blocks: co-residency safe)
  void* args[] = {
    (void*)&eidx, (void*)&eattr, (void*)&we, (void*)&be,
    (void*)&lin1, (void*)&line1, (void*)&as1, (void*)&ad1, (void*)&ae1,
    (void*)&lin2, (void*)&line2, (void*)&as2, (void*)&ad2, (void*)&ae2,
    (void*)&vS, (void*)&vD, (void*)&vE,
    (void*)&deg, (void*)&cnt, (void*)&rowptr, (void*)&bsum,
    (void*)&eid, (void*)&srcs, (void*)&aeg1c, (void*)&aeg2c,
    (void*)&n, (void*)&E
  };
  hipLaunchCooperativeKernel((void*)k_prep, dim3(512), dim3(256), args, 0, stream);

  // layer 1 (x1 GEMM + att dots fused into the h GEMM)
  k_hx1<<<(n + 15) / 16, 256, 0, stream>>>(x, wn, bn, vS, vD, lin1, h_bf,
                                           ssrc1, sdst1, n);
  k_node<true><<<(n + 3) / 4, 256, 0, stream>>>(h_bf, ssrc1, sdst1, aeg1c,
      rowptr, eid, srcs, b1, g1, bt1, vS + 256, vD + 256,
      alpha1, h1, ssrc2, sdst2, n, E);
  // layer 2
  k_h<<<(n + 15) / 16, 256, 0, stream>>>(h1, lin2, h_bf, n);
  k_node<false><<<(n + 3) / 4, 256, 0, stream>>>(h_bf, ssrc2, sdst2, aeg2c,
      rowptr, eid, srcs, b2, g2, bt2, nullptr, nullptr,
      alpha2, out_h2, nullptr, nullptr, n, E);
}

// Round 12
// 208.117 us; speedup vs baseline: 2.3275x; 2.3275x over previous
//
#include <hip/hip_runtime.h>

#define FN 32
#define FE 16
#define HID 64
#define HEADS 4
#define CHC 64
// H*C = 256

typedef float f32x4 __attribute__((ext_vector_type(4)));

__device__ __forceinline__ float bf2f(unsigned short u) {
  unsigned int x = ((unsigned int)u) << 16;
  return __builtin_bit_cast(float, x);
}
__device__ __forceinline__ unsigned short f2bf(float f) {
  unsigned int x = __builtin_bit_cast(unsigned int, f);
  unsigned int r = (x + 0x7fff + ((x >> 16) & 1)) >> 16;   // RNE
  return (unsigned short)r;
}
__device__ __forceinline__ unsigned int pack2bf(float a, float b) {
  return (unsigned int)f2bf(a) | ((unsigned int)f2bf(b) << 16);
}

// fold vectors (blocks 0..5) + degree count (all blocks). grid = edge grid.
__global__ __launch_bounds__(256) void k_vecs_deg(
    const int* __restrict__ dst,
    const float* __restrict__ lin1, const float* __restrict__ line1,
    const float* __restrict__ as1, const float* __restrict__ ad1,
    const float* __restrict__ ae1,
    const float* __restrict__ lin2, const float* __restrict__ line2,
    const float* __restrict__ as2, const float* __restrict__ ad2,
    const float* __restrict__ ae2,
    float* __restrict__ vS, float* __restrict__ vD, float* __restrict__ vE,
    int* __restrict__ deg, int E)
{
  int b = blockIdx.x, t = threadIdx.x;
  if (b < 6) {
    int l = b / 3, kind = b % 3;
    const float* lin = (kind == 2) ? (l ? line2 : line1) : (l ? lin2 : lin1);
    const float* att = (kind == 0) ? (l ? as2 : as1)
                     : (kind == 1) ? (l ? ad2 : ad1) : (l ? ae2 : ae1);
    float* out = ((kind == 0) ? vS : (kind == 1) ? vD : vE) + l * 256;
    int c = t >> 2, hd = t & 3;
    float acc = 0.f;
    for (int cc = 0; cc < CHC; cc++)
      acc += lin[c * (HEADS * CHC) + hd * CHC + cc] * att[hd * CHC + cc];
    out[c * 4 + hd] = acc;
  }
  int e = b * 256 + t;
  if (e < E) atomicAdd(&deg[dst[e]], 1);
}

// ---- scan kernels: per-block scan + fused block-offset apply ----
__global__ __launch_bounds__(1024) void k_scan1(const int* __restrict__ deg,
    int* __restrict__ rowptr, int* __restrict__ bsum, int n)
{
  __shared__ int wsum[16];
  int t = threadIdx.x, wv = t >> 6, lane = t & 63;
  int i = blockIdx.x * 1024 + t;
  int val = (i < n) ? deg[i] : 0;
  int sc = val;
  #pragma unroll
  for (int off = 1; off < 64; off <<= 1) {
    int u = __shfl_up(sc, off);
    if (lane >= off) sc += u;
  }
  if (lane == 63) wsum[wv] = sc;
  __syncthreads();
  int woff = 0;
  #pragma unroll
  for (int k = 0; k < 16; k++) woff += (k < wv) ? wsum[k] : 0;
  if (i < n) rowptr[i] = woff + sc - val;
  if (t == 0) {
    int tot = 0;
    #pragma unroll
    for (int k = 0; k < 16; k++) tot += wsum[k];
    bsum[blockIdx.x] = tot;
  }
}

// apply block offsets + copy rowptr->cnt + rowptr[n]
__global__ __launch_bounds__(1024) void k_scan23(const int* __restrict__ bsum,
    int* __restrict__ rowptr, int* __restrict__ cnt, int nb, int n)
{
  int b = blockIdx.x;
  int t = threadIdx.x;
  int off = 0;
  for (int j = 0; j < b; j++) off += bsum[j];
  int i = b * 1024 + t;
  if (i < n) {
    int rv = rowptr[i] + off;
    rowptr[i] = rv;
    cnt[i] = rv;
  }
  if (b == 0 && t == 0) {
    int tot = 0;
    for (int j = 0; j < nb; j++) tot += bsum[j];
    rowptr[n] = tot;
  }
}

// CSR fill + edge a_edge fused (no perm array). Lane-owns-edge.
__global__ __launch_bounds__(256) void k_fill_aeg(const int* __restrict__ src,
    const int* __restrict__ dst, const float* __restrict__ eattr,
    const float* __restrict__ we, const float* __restrict__ be,
    const float* __restrict__ vE, int* __restrict__ cnt,
    int* __restrict__ eid, int* __restrict__ srcs,
    float* __restrict__ aeg1, float* __restrict__ aeg2, int E)
{
  __shared__ float4 we_t4[HID][4];
  __shared__ float4 vE_s[2][HID];
  __shared__ float  be_s[HID];
  int t = threadIdx.x;
  for (int i = t; i < FE * HID; i += 256) {
    int k = i >> 6, c = i & 63;
    ((float*)we_t4)[c * 16 + k] = we[i];
  }
  for (int i = t; i < 512; i += 256) ((float*)vE_s)[i] = vE[i];
  if (t < HID) be_s[t] = be[t];
  __syncthreads();

  int e = blockIdx.x * 256 + t;
  if (e >= E) return;
  int d = dst[e];
  int pos = atomicAdd(&cnt[d], 1);
  eid[pos] = e;
  srcs[pos] = src[e];
  const float4* er = (const float4*)(eattr + (size_t)e * FE);
  float4 A = er[0], B = er[1], C4 = er[2], D = er[3];
  float ta[FE] = {A.x, A.y, A.z, A.w, B.x, B.y, B.z, B.w,
                  C4.x, C4.y, C4.z, C4.w, D.x, D.y, D.z, D.w};
  float4 acc1 = make_float4(0.f, 0.f, 0.f, 0.f);
  float4 acc2 = make_float4(0.f, 0.f, 0.f, 0.f);
  #pragma unroll 4
  for (int c = 0; c < HID; c++) {
    float4 w0 = we_t4[c][0], w1 = we_t4[c][1], w2 = we_t4[c][2], w3 = we_t4[c][3];
    float ea = be_s[c];
    ea += ta[0] * w0.x + ta[1] * w0.y + ta[2] * w0.z + ta[3] * w0.w;
    ea += ta[4] * w1.x + ta[5] * w1.y + ta[6] * w1.z + ta[7] * w1.w;
    ea += ta[8] * w2.x + ta[9] * w2.y + ta[10] * w2.z + ta[11] * w2.w;
    ea += ta[12] * w3.x + ta[13] * w3.y + ta[14] * w3.z + ta[15] * w3.w;
    ea = fmaxf(ea, 0.f);
    float4 u1 = vE_s[0][c], u2 = vE_s[1][c];
    acc1.x += ea * u1.x; acc1.y += ea * u1.y; acc1.z += ea * u1.z; acc1.w += ea * u1.w;
    acc2.x += ea * u2.x; acc2.y += ea * u2.y; acc2.z += ea * u2.z; acc2.w += ea * u2.w;
  }
  *(float4*)(aeg1 + (size_t)pos * 4) = acc1;
  *(float4*)(aeg2 + (size_t)pos * 4) = acc2;
}

// Fused layer-1 front-end: x1 = relu(x@wn+bn) (LDS only) + att dots +
// h(bf16) = x1 @ lin. 16 nodes/block.
__global__ __launch_bounds__(256) void k_hx1(const float* __restrict__ x,
    const float* __restrict__ wn, const float* __restrict__ bn,
    const float* __restrict__ vS, const float* __restrict__ vD,
    const float* __restrict__ lin, unsigned short* __restrict__ h_bf,
    float* __restrict__ ssrc, float* __restrict__ sdst, int n)
{
  int t = threadIdx.x, wv = t >> 6, lane = t & 63;
  int v0 = blockIdx.x * 16;
  __shared__ float xin_s[16][FN];
  __shared__ float xs[16][HID];
  if (t < 128) {
    int node = t >> 3, c4 = (t & 7) * 4;
    int vv = v0 + node;
    float4 val = make_float4(0.f, 0.f, 0.f, 0.f);
    if (vv < n) val = *(const float4*)(x + (size_t)vv * FN + c4);
    *(float4*)&xin_s[node][c4] = val;
  }
  __syncthreads();
  {
    int nd = t >> 4, cg_ = t & 15;
    int vv = v0 + nd;
    const float4* wn4 = (const float4*)wn;
    float4 a = ((const float4*)bn)[cg_];
    #pragma unroll 8
    for (int k = 0; k < FN; k++) {
      float xv = xin_s[nd][k];
      float4 w = wn4[k * 16 + cg_];
      a.x += xv * w.x; a.y += xv * w.y; a.z += xv * w.z; a.w += xv * w.w;
    }
    a.x = fmaxf(a.x, 0.f); a.y = fmaxf(a.y, 0.f);
    a.z = fmaxf(a.z, 0.f); a.w = fmaxf(a.w, 0.f);
    *(float4*)&xs[nd][cg_ * 4] = a;
    const float4* vS4 = (const float4*)vS;
    const float4* vD4 = (const float4*)vD;
    int c0 = cg_ * 4;
    float4 vs0 = vS4[c0], vs1 = vS4[c0 + 1], vs2 = vS4[c0 + 2], vs3 = vS4[c0 + 3];
    float4 vd0 = vD4[c0], vd1 = vD4[c0 + 1], vd2 = vD4[c0 + 2], vd3 = vD4[c0 + 3];
    float pS[4], pD[4];
    pS[0] = a.x * vs0.x + a.y * vs1.x + a.z * vs2.x + a.w * vs3.x;
    pS[1] = a.x * vs0.y + a.y * vs1.y + a.z * vs2.y + a.w * vs3.y;
    pS[2] = a.x * vs0.z + a.y * vs1.z + a.z * vs2.z + a.w * vs3.z;
    pS[3] = a.x * vs0.w + a.y * vs1.w + a.z * vs2.w + a.w * vs3.w;
    pD[0] = a.x * vd0.x + a.y * vd1.x + a.z * vd2.x + a.w * vd3.x;
    pD[1] = a.x * vd0.y + a.y * vd1.y + a.z * vd2.y + a.w * vd3.y;
    pD[2] = a.x * vd0.z + a.y * vd1.z + a.z * vd2.z + a.w * vd3.z;
    pD[3] = a.x * vd0.w + a.y * vd1.w + a.z * vd2.w + a.w * vd3.w;
    #pragma unroll
    for (int off = 1; off < 16; off <<= 1) {
      #pragma unroll
      for (int h = 0; h < 4; h++) {
        pS[h] += __shfl_xor(pS[h], off);
        pD[h] += __shfl_xor(pD[h], off);
      }
    }
    if (cg_ == 0 && vv < n) {
      *(float4*)(ssrc + (size_t)vv * 4) = make_float4(pS[0], pS[1], pS[2], pS[3]);
      *(float4*)(sdst + (size_t)vv * 4) = make_float4(pD[0], pD[1], pD[2], pD[3]);
    }
  }
  __syncthreads();
  float acc[4][4];
  #pragma unroll
  for (int i = 0; i < 4; i++)
    #pragma unroll
    for (int j = 0; j < 4; j++) acc[i][j] = 0.f;
  const float4* lin4 = (const float4*)lin;
  int nd0 = wv * 4;
  #pragma unroll 4
  for (int kb = 0; kb < 16; kb++) {
    float4 xv[4];
    #pragma unroll
    for (int i = 0; i < 4; i++) xv[i] = *(const float4*)&xs[nd0 + i][kb * 4];
    float4 lv0 = lin4[(kb * 4 + 0) * 64 + lane];
    float4 lv1 = lin4[(kb * 4 + 1) * 64 + lane];
    float4 lv2 = lin4[(kb * 4 + 2) * 64 + lane];
    float4 lv3 = lin4[(kb * 4 + 3) * 64 + lane];
    #pragma unroll
    for (int i = 0; i < 4; i++) {
      acc[i][0] += xv[i].x * lv0.x + xv[i].y * lv1.x + xv[i].z * lv2.x + xv[i].w * lv3.x;
      acc[i][1] += xv[i].x * lv0.y + xv[i].y * lv1.y + xv[i].z * lv2.y + xv[i].w * lv3.y;
      acc[i][2] += xv[i].x * lv0.z + xv[i].y * lv1.z + xv[i].z * lv2.z + xv[i].w * lv3.z;
      acc[i][3] += xv[i].x * lv0.w + xv[i].y * lv1.w + xv[i].z * lv2.w + xv[i].w * lv3.w;
    }
  }
  #pragma unroll
  for (int i = 0; i < 4; i++) {
    int v = v0 + nd0 + i;
    if (v < n) {
      uint2 u;
      u.x = pack2bf(acc[i][0], acc[i][1]);
      u.y = pack2bf(acc[i][2], acc[i][3]);
      *(uint2*)(h_bf + (size_t)v * 256 + lane * 4) = u;
    }
  }
}

// h(bf16) = x @ lin [n,256]. 16 nodes/block; thread = 4 nodes x 4 channels.
__global__ __launch_bounds__(256) void k_h(const float* __restrict__ xin,
    const float* __restrict__ lin, unsigned short* __restrict__ h_bf, int n)
{
  int t = threadIdx.x, wv = t >> 6, lane = t & 63;
  int v0 = blockIdx.x * 16;
  __shared__ float xs[16][HID];
  {
    int node = t >> 4, ch4 = (t & 15) * 4;
    int vv = v0 + node;
    float4 val = make_float4(0.f, 0.f, 0.f, 0.f);
    if (vv < n) val = *(const float4*)(xin + (size_t)vv * HID + ch4);
    *(float4*)&xs[node][ch4] = val;
  }
  __syncthreads();
  float acc[4][4];
  #pragma unroll
  for (int i = 0; i < 4; i++)
    #pragma unroll
    for (int j = 0; j < 4; j++) acc[i][j] = 0.f;
  const float4* lin4 = (const float4*)lin;
  int nd0 = wv * 4;
  #pragma unroll 4
  for (int kb = 0; kb < 16; kb++) {
    float4 xv[4];
    #pragma unroll
    for (int i = 0; i < 4; i++) xv[i] = *(const float4*)&xs[nd0 + i][kb * 4];
    float4 lv0 = lin4[(kb * 4 + 0) * 64 + lane];
    float4 lv1 = lin4[(kb * 4 + 1) * 64 + lane];
    float4 lv2 = lin4[(kb * 4 + 2) * 64 + lane];
    float4 lv3 = lin4[(kb * 4 + 3) * 64 + lane];
    #pragma unroll
    for (int i = 0; i < 4; i++) {
      acc[i][0] += xv[i].x * lv0.x + xv[i].y * lv1.x + xv[i].z * lv2.x + xv[i].w * lv3.x;
      acc[i][1] += xv[i].x * lv0.y + xv[i].y * lv1.y + xv[i].z * lv2.y + xv[i].w * lv3.y;
      acc[i][2] += xv[i].x * lv0.z + xv[i].y * lv1.z + xv[i].z * lv2.z + xv[i].w * lv3.z;
      acc[i][3] += xv[i].x * lv0.w + xv[i].y * lv1.w + xv[i].z * lv2.w + xv[i].w * lv3.w;
    }
  }
  #pragma unroll
  for (int i = 0; i < 4; i++) {
    int v = v0 + nd0 + i;
    if (v < n) {
      uint2 u;
      u.x = pack2bf(acc[i][0], acc[i][1]);
      u.y = pack2bf(acc[i][2], acc[i][3]);
      *(uint2*)(h_bf + (size_t)v * 256 + lane * 4) = u;
    }
  }
}

// Fused per-node: self-loop aeg (inline wave-mean) + softmax + alpha +
// aggregation + head-mean + bias + leaky + LayerNorm (+ next-layer dots).
// WAVE per node, R7-best structure.
template<bool DOTS>
__global__ __launch_bounds__(256) void k_node(
    const unsigned short* __restrict__ h_bf, const float* __restrict__ ssrc,
    const float* __restrict__ sdst, const float* __restrict__ aegc,
    const int* __restrict__ rowptr, const int* __restrict__ eidArr,
    const int* __restrict__ srcs, const float* __restrict__ bias,
    const float* __restrict__ gamma, const float* __restrict__ beta,
    const float* __restrict__ vS2, const float* __restrict__ vD2,
    float* __restrict__ alpha_out, float* __restrict__ xout,
    float* __restrict__ ssrc_o, float* __restrict__ sdst_o, int n, int E)
{
  __shared__ float als[4][64][4];   // per-wave alpha exchange (conflict-free)
  int t = threadIdx.x; int wv = t >> 6, lane = t & 63;
  int v = blockIdx.x * 4 + wv;
  if (v >= n) return;
  int r0 = rowptr[v], r1 = rowptr[v + 1];
  int deg = r1 - r0, ne = deg + 1;      // + self loop (edge id E+v, src v)
  int coff = lane * 4;                  // aggregation: 4 channels per lane
  int hh = lane >> 4;                   // head owning those channels
  float acc0 = 0.f, acc1 = 0.f, acc2 = 0.f, acc3 = 0.f;
  const float4* aeg4 = (const float4*)aegc;
  const float4* ss4p = (const float4*)ssrc;
  float4 sd4 = ((const float4*)sdst)[v];

  if (ne <= 64) {
    int s = v, eo = E + v;
    if (lane < deg) { s = srcs[r0 + lane]; eo = eidArr[r0 + lane]; }
    bool valid = (lane < ne);
    float4 ae4 = make_float4(0.f, 0.f, 0.f, 0.f);
    if (lane < deg) ae4 = aeg4[r0 + lane];
    // self-loop aeg = mean of edge aeg over the neighborhood (wave-sum)
    {
      float sx = ae4.x, sy = ae4.y, sz = ae4.z, sw = ae4.w;
      #pragma unroll
      for (int off = 1; off < 64; off <<= 1) {
        sx += __shfl_xor(sx, off);
        sy += __shfl_xor(sy, off);
        sz += __shfl_xor(sz, off);
        sw += __shfl_xor(sw, off);
      }
      float inv = 1.f / fmaxf((float)deg, 1.f);
      if (lane == deg) ae4 = make_float4(sx * inv, sy * inv, sz * inv, sw * inv);
    }
    float4 ss4 = ss4p[s];
    float a0 = -INFINITY, a1 = -INFINITY, a2 = -INFINITY, a3 = -INFINITY;
    if (valid) {
      a0 = ss4.x + sd4.x + ae4.x; a0 = (a0 > 0.f) ? a0 : 0.2f * a0;
      a1 = ss4.y + sd4.y + ae4.y; a1 = (a1 > 0.f) ? a1 : 0.2f * a1;
      a2 = ss4.z + sd4.z + ae4.z; a2 = (a2 > 0.f) ? a2 : 0.2f * a2;
      a3 = ss4.w + sd4.w + ae4.w; a3 = (a3 > 0.f) ? a3 : 0.2f * a3;
    }
    float m0, m1, m2, m3;
    {
      bool hi0 = lane & 1;
      float k0 = hi0 ? a2 : a0, s0 = hi0 ? a0 : a2;
      float k1 = hi0 ? a3 : a1, s1 = hi0 ? a1 : a3;
      float q0 = fmaxf(k0, __shfl_xor(s0, 1));
      float q1 = fmaxf(k1, __shfl_xor(s1, 1));
      bool hi1 = lane & 2;
      float k2 = hi1 ? q1 : q0, s2 = hi1 ? q0 : q1;
      float r = fmaxf(k2, __shfl_xor(s2, 2));
      r = fmaxf(r, __shfl_xor(r, 4));
      r = fmaxf(r, __shfl_xor(r, 8));
      r = fmaxf(r, __shfl_xor(r, 16));
      r = fmaxf(r, __shfl_xor(r, 32));
      m0 = __shfl(r, 0); m1 = __shfl(r, 2); m2 = __shfl(r, 1); m3 = __shfl(r, 3);
    }
    float e0 = __expf(a0 - m0), e1 = __expf(a1 - m1);
    float e2 = __expf(a2 - m2), e3 = __expf(a3 - m3);
    float d0, d1, d2, d3;
    {
      bool hi0 = lane & 1;
      float k0 = hi0 ? e2 : e0, s0 = hi0 ? e0 : e2;
      float k1 = hi0 ? e3 : e1, s1 = hi0 ? e1 : e3;
      float q0 = k0 + __shfl_xor(s0, 1);
      float q1 = k1 + __shfl_xor(s1, 1);
      bool hi1 = lane & 2;
      float k2 = hi1 ? q1 : q0, s2 = hi1 ? q0 : q1;
      float r = k2 + __shfl_xor(s2, 2);
      r += __shfl_xor(r, 4);
      r += __shfl_xor(r, 8);
      r += __shfl_xor(r, 16);
      r += __shfl_xor(r, 32);
      d0 = __shfl(r, 0); d1 = __shfl(r, 2); d2 = __shfl(r, 1); d3 = __shfl(r, 3);
    }
    float4 alf = make_float4(e0 / d0, e1 / d1, e2 / d2, e3 / d3);
    if (valid) {
      f32x4 alv = {alf.x, alf.y, alf.z, alf.w};
      __builtin_nontemporal_store(alv, (f32x4*)alpha_out + eo);
    }
    *(float4*)als[wv][lane] = alf;
    __builtin_amdgcn_wave_barrier();
    __builtin_amdgcn_sched_barrier(0);
    int jj = 0;
    for (; jj + 3 < ne; jj += 4) {
      int s0 = __shfl(s, jj), s1 = __shfl(s, jj + 1);
      int s2 = __shfl(s, jj + 2), s3 = __shfl(s, jj + 3);
      float al0 = als[wv][jj][hh],     al1 = als[wv][jj + 1][hh];
      float al2 = als[wv][jj + 2][hh], al3 = als[wv][jj + 3][hh];
      uint2 u0 = *(const uint2*)(h_bf + (size_t)s0 * 256 + coff);
      uint2 u1 = *(const uint2*)(h_bf + (size_t)s1 * 256 + coff);
      uint2 u2 = *(const uint2*)(h_bf + (size_t)s2 * 256 + coff);
      uint2 u3 = *(const uint2*)(h_bf + (size_t)s3 * 256 + coff);
      acc0 += al0 * bf2f((unsigned short)(u0.x & 0xffff))
            + al1 * bf2f((unsigned short)(u1.x & 0xffff))
            + al2 * bf2f((unsigned short)(u2.x & 0xffff))
            + al3 * bf2f((unsigned short)(u3.x & 0xffff));
      acc1 += al0 * bf2f((unsigned short)(u0.x >> 16))
            + al1 * bf2f((unsigned short)(u1.x >> 16))
            + al2 * bf2f((unsigned short)(u2.x >> 16))
            + al3 * bf2f((unsigned short)(u3.x >> 16));
      acc2 += al0 * bf2f((unsigned short)(u0.y & 0xffff))
            + al1 * bf2f((unsigned short)(u1.y & 0xffff))
            + al2 * bf2f((unsigned short)(u2.y & 0xffff))
            + al3 * bf2f((unsigned short)(u3.y & 0xffff));
      acc3 += al0 * bf2f((unsigned short)(u0.y >> 16))
            + al1 * bf2f((unsigned short)(u1.y >> 16))
            + al2 * bf2f((unsigned short)(u2.y >> 16))
            + al3 * bf2f((unsigned short)(u3.y >> 16));
    }
    for (; jj < ne; jj++) {
      int s0 = __shfl(s, jj);
      float al0 = als[wv][jj][hh];
      uint2 u0 = *(const uint2*)(h_bf + (size_t)s0 * 256 + coff);
      acc0 += al0 * bf2f((unsigned short)(u0.x & 0xffff));
      acc1 += al0 * bf2f((unsigned short)(u0.x >> 16));
      acc2 += al0 * bf2f((unsigned short)(u0.y & 0xffff));
      acc3 += al0 * bf2f((unsigned short)(u0.y >> 16));
    }
  } else {
    // ---- chunked two-pass fallback (deg > 63, rare) ----
    int j4 = lane >> 2, hb = lane & 3;
    float sd = sdst[v * 4 + hb];
    // self-loop aeg (per-hb): strided sum over edges
    float selfae;
    {
      float msum = 0.f;
      for (int jc = j4; jc < deg; jc += 16)
        msum += aegc[(size_t)(r0 + jc) * 4 + hb];
      msum += __shfl_xor(msum, 4);
      msum += __shfl_xor(msum, 8);
      msum += __shfl_xor(msum, 16);
      msum += __shfl_xor(msum, 32);
      selfae = msum / fmaxf((float)deg, 1.f);
    }
    float m = -INFINITY;
    for (int jb = 0; jb < ne; jb += 16) {
      int jc = jb + j4;
      if (jc < ne) {
        int s2 = (jc < deg) ? srcs[r0 + jc] : v;
        float ae = (jc < deg) ? aegc[(size_t)(r0 + jc) * 4 + hb] : selfae;
        float a = ssrc[s2 * 4 + hb] + sd + ae;
        a = (a > 0.f) ? a : 0.2f * a;
        m = fmaxf(m, a);
      }
    }
    m = fmaxf(m, __shfl_xor(m, 4));
    m = fmaxf(m, __shfl_xor(m, 8));
    m = fmaxf(m, __shfl_xor(m, 16));
    m = fmaxf(m, __shfl_xor(m, 32));
    float den = 0.f;
    for (int jb = 0; jb < ne; jb += 16) {
      int jc = jb + j4;
      if (jc < ne) {
        int s2 = (jc < deg) ? srcs[r0 + jc] : v;
        float ae = (jc < deg) ? aegc[(size_t)(r0 + jc) * 4 + hb] : selfae;
        float a = ssrc[s2 * 4 + hb] + sd + ae;
        a = (a > 0.f) ? a : 0.2f * a;
        den += __expf(a - m);
      }
    }
    den += __shfl_xor(den, 4);
    den += __shfl_xor(den, 8);
    den += __shfl_xor(den, 16);
    den += __shfl_xor(den, 32);
    float rden = 1.f / den;
    for (int jb = 0; jb < ne; jb += 16) {
      int jc = jb + j4;
      if (jc < ne) {
        int s2 = (jc < deg) ? srcs[r0 + jc] : v;
        int eo = (jc < deg) ? eidArr[r0 + jc] : E + v;
        float ae = (jc < deg) ? aegc[(size_t)(r0 + jc) * 4 + hb] : selfae;
        float a = ssrc[s2 * 4 + hb] + sd + ae;
        a = (a > 0.f) ? a : 0.2f * a;
        alpha_out[(size_t)eo * 4 + hb] = __expf(a - m) * rden;
      }
    }
    float sdh = __shfl(sd, hh);
    float mh  = __shfl(m, hh);
    float rdh = __shfl(rden, hh);
    float selfh = __shfl(selfae, hh);
    for (int jc = 0; jc < ne; jc++) {
      int s0 = (jc < deg) ? srcs[r0 + jc] : v;
      float ae = (jc < deg) ? aegc[(size_t)(r0 + jc) * 4 + hh] : selfh;
      float a = ssrc[s0 * 4 + hh] + sdh + ae;
      a = (a > 0.f) ? a : 0.2f * a;
      float al = __expf(a - mh) * rdh;
      uint2 u = *(const uint2*)(h_bf + (size_t)s0 * 256 + coff);
      acc0 += al * bf2f((unsigned short)(u.x & 0xffff));
      acc1 += al * bf2f((unsigned short)(u.x >> 16));
      acc2 += al * bf2f((unsigned short)(u.y & 0xffff));
      acc3 += al * bf2f((unsigned short)(u.y >> 16));
    }
  }

  // ---- head reduce: lanes {L, L+16, L+32, L+48} hold heads 0..3 ----
  acc0 += __shfl_xor(acc0, 16); acc0 += __shfl_xor(acc0, 32);
  acc1 += __shfl_xor(acc1, 16); acc1 += __shfl_xor(acc1, 32);
  acc2 += __shfl_xor(acc2, 16); acc2 += __shfl_xor(acc2, 32);
  acc3 += __shfl_xor(acc3, 16); acc3 += __shfl_xor(acc3, 32);

  // ---- epilogue: bias + leaky(0.01) + LayerNorm(64); all lanes hold copy ----
  int c16 = lane & 15;
  float4 b4 = ((const float4*)bias)[c16];
  float v0 = acc0 * 0.25f + b4.x;
  float v1 = acc1 * 0.25f + b4.y;
  float v2 = acc2 * 0.25f + b4.z;
  float v3 = acc3 * 0.25f + b4.w;
  v0 = (v0 > 0.f) ? v0 : 0.01f * v0;
  v1 = (v1 > 0.f) ? v1 : 0.01f * v1;
  v2 = (v2 > 0.f) ? v2 : 0.01f * v2;
  v3 = (v3 > 0.f) ? v3 : 0.01f * v3;
  float mu = v0 + v1 + v2 + v3;
  mu += __shfl_xor(mu, 1); mu += __shfl_xor(mu, 2);
  mu += __shfl_xor(mu, 4); mu += __shfl_xor(mu, 8);
  mu *= (1.f / 64.f);
  float d0 = v0 - mu, d1 = v1 - mu, d2 = v2 - mu, d3 = v3 - mu;
  float var = d0 * d0 + d1 * d1 + d2 * d2 + d3 * d3;
  var += __shfl_xor(var, 1); var += __shfl_xor(var, 2);
  var += __shfl_xor(var, 4); var += __shfl_xor(var, 8);
  var *= (1.f / 64.f);
  float rstd = rsqrtf(var + 1e-5f);
  float4 g4 = ((const float4*)gamma)[c16];
  float4 be4 = ((const float4*)beta)[c16];
  float y0 = d0 * rstd * g4.x + be4.x;
  float y1 = d1 * rstd * g4.y + be4.y;
  float y2 = d2 * rstd * g4.z + be4.z;
  float y3 = d3 * rstd * g4.w + be4.w;
  if (lane < 16) {
    float4 y = make_float4(y0, y1, y2, y3);
    *(float4*)(xout + (size_t)v * HID + lane * 4) = y;
  }
  if constexpr (DOTS) {
    // next-layer att dots: p_h = y . vS2[:,h]; 16-lane reduce = ONE full copy
    int c0 = c16 * 4;
    float4 vs0 = ((const float4*)vS2)[c0],     vs1 = ((const float4*)vS2)[c0 + 1];
    float4 vs2 = ((const float4*)vS2)[c0 + 2], vs3 = ((const float4*)vS2)[c0 + 3];
    float4 vd0 = ((const float4*)vD2)[c0],     vd1 = ((const float4*)vD2)[c0 + 1];
    float4 vd2 = ((const float4*)vD2)[c0 + 2], vd3 = ((const float4*)vD2)[c0 + 3];
    float pS[4], pD[4];
    pS[0] = y0 * vs0.x + y1 * vs1.x + y2 * vs2.x + y3 * vs3.x;
    pS[1] = y0 * vs0.y + y1 * vs1.y + y2 * vs2.y + y3 * vs3.y;
    pS[2] = y0 * vs0.z + y1 * vs1.z + y2 * vs2.z + y3 * vs3.z;
    pS[3] = y0 * vs0.w + y1 * vs1.w + y2 * vs2.w + y3 * vs3.w;
    pD[0] = y0 * vd0.x + y1 * vd1.x + y2 * vd2.x + y3 * vd3.x;
    pD[1] = y0 * vd0.y + y1 * vd1.y + y2 * vd2.y + y3 * vd3.y;
    pD[2] = y0 * vd0.z + y1 * vd1.z + y2 * vd2.z + y3 * vd3.z;
    pD[3] = y0 * vd0.w + y1 * vd1.w + y2 * vd2.w + y3 * vd3.w;
    #pragma unroll
    for (int off = 1; off < 16; off <<= 1) {
      #pragma unroll
      for (int h = 0; h < 4; h++) {
        pS[h] += __shfl_xor(pS[h], off);
        pD[h] += __shfl_xor(pD[h], off);
      }
    }
    if (lane == 0) {
      *(float4*)(ssrc_o + (size_t)v * 4) = make_float4(pS[0], pS[1], pS[2], pS[3]);
      *(float4*)(sdst_o + (size_t)v * 4) = make_float4(pD[0], pD[1], pD[2], pD[3]);
    }
  }
}

extern "C" void kernel_launch(void* const* d_in, const int* in_sizes, int n_in,
                              void* d_out, int out_size, void* d_ws, size_t ws_size,
                              hipStream_t stream)
{
  const float* x     = (const float*)d_in[0];
  const int*   eidx  = (const int*)d_in[1];
  const float* eattr = (const float*)d_in[2];
  const float* wn    = (const float*)d_in[3];
  const float* bn    = (const float*)d_in[4];
  const float* we    = (const float*)d_in[5];
  const float* be    = (const float*)d_in[6];
  const float* lin1  = (const float*)d_in[7];
  const float* line1 = (const float*)d_in[8];
  const float* as1   = (const float*)d_in[9];
  const float* ad1   = (const float*)d_in[10];
  const float* ae1   = (const float*)d_in[11];
  const float* b1    = (const float*)d_in[12];
  const float* g1    = (const float*)d_in[13];
  const float* bt1   = (const float*)d_in[14];
  const float* lin2  = (const float*)d_in[15];
  const float* line2 = (const float*)d_in[16];
  const float* as2   = (const float*)d_in[17];
  const float* ad2   = (const float*)d_in[18];
  const float* ae2   = (const float*)d_in[19];
  const float* b2    = (const float*)d_in[20];
  const float* g2    = (const float*)d_in[21];
  const float* bt2   = (const float*)d_in[22];

  int n = in_sizes[0] / FN;
  int E = in_sizes[1] / 2;
  const int* srcA = eidx;
  const int* dstA = eidx + E;

  float* out_h2 = (float*)d_out;
  float* alpha1 = out_h2 + (size_t)n * HID;
  float* alpha2 = alpha1 + (size_t)(E + n) * 4;

  char* ws = (char*)d_ws;
  size_t off = 0;
  auto alloc = [&](size_t bytes) -> char* {
    char* p = ws + off;
    off += (bytes + 255) & ~(size_t)255;
    return p;
  };
  unsigned short* h_bf = (unsigned short*)alloc((size_t)n * 256 * 2);
  float* h1      = (float*)alloc((size_t)n * HID * 4);
  float* aeg1c   = (float*)alloc((size_t)E * 4 * 4);
  float* aeg2c   = (float*)alloc((size_t)E * 4 * 4);
  float* ssrc1   = (float*)alloc((size_t)n * 4 * 4);
  float* sdst1   = (float*)alloc((size_t)n * 4 * 4);
  float* ssrc2   = (float*)alloc((size_t)n * 4 * 4);
  float* sdst2   = (float*)alloc((size_t)n * 4 * 4);
  float* vS      = (float*)alloc(512 * 4);
  float* vD      = (float*)alloc(512 * 4);
  float* vE      = (float*)alloc(512 * 4);
  int*   deg     = (int*)alloc((size_t)n * 4);
  int*   cnt     = (int*)alloc((size_t)n * 4);
  int*   rowptr  = (int*)alloc((size_t)(n + 1) * 4);
  int*   eid     = (int*)alloc((size_t)E * 4);
  int*   srcs    = (int*)alloc((size_t)E * 4);
  int*   bsum    = (int*)alloc(1024 * 4);

  hipMemsetAsync(deg, 0, (size_t)n * 4, stream);

  int nb = (n + 1023) / 1024;
  k_vecs_deg<<<(E + 255) / 256, 256, 0, stream>>>(dstA,
      lin1, line1, as1, ad1, ae1, lin2, line2, as2, ad2, ae2,
      vS, vD, vE, deg, E);
  k_scan1<<<nb, 1024, 0, stream>>>(deg, rowptr, bsum, n);
  k_scan23<<<nb, 1024, 0, stream>>>(bsum, rowptr, cnt, nb, n);
  k_fill_aeg<<<(E + 255) / 256, 256, 0, stream>>>(srcA, dstA, eattr, we, be,
      vE, cnt, eid, srcs, aeg1c, aeg2c, E);

  // layer 1 (x1 GEMM + att dots fused into the h GEMM)
  k_hx1<<<(n + 15) / 16, 256, 0, stream>>>(x, wn, bn, vS, vD, lin1, h_bf,
                                           ssrc1, sdst1, n);
  k_node<true><<<(n + 3) / 4, 256, 0, stream>>>(h_bf, ssrc1, sdst1, aeg1c,
      rowptr, eid, srcs, b1, g1, bt1, vS + 256, vD + 256,
      alpha1, h1, ssrc2, sdst2, n, E);
  // layer 2
  k_h<<<(n + 15) / 16, 256, 0, stream>>>(h1, lin2, h_bf, n);
  k_node<false><<<(n + 3) / 4, 256, 0, stream>>>(h_bf, ssrc2, sdst2, aeg2c,
      rowptr, eid, srcs, b2, g2, bt2, nullptr, nullptr,
      alpha2, out_h2, nullptr, nullptr, n, E);
}

// Round 13
// 205.355 us; speedup vs baseline: 2.3588x; 1.0134x over previous
//
#include <hip/hip_runtime.h>

#define FN 32
#define FE 16
#define HID 64
#define HEADS 4
#define CHC 64
// H*C = 256

typedef float f32x4 __attribute__((ext_vector_type(4)));

__device__ __forceinline__ float bf2f(unsigned short u) {
  unsigned int x = ((unsigned int)u) << 16;
  return __builtin_bit_cast(float, x);
}
__device__ __forceinline__ unsigned short f2bf(float f) {
  unsigned int x = __builtin_bit_cast(unsigned int, f);
  unsigned int r = (x + 0x7fff + ((x >> 16) & 1)) >> 16;   // RNE
  return (unsigned short)r;
}
__device__ __forceinline__ unsigned int pack2bf(float a, float b) {
  return (unsigned int)f2bf(a) | ((unsigned int)f2bf(b) << 16);
}

// fold vectors (blocks 0..5) + degree count (all blocks). grid = edge grid.
__global__ __launch_bounds__(256) void k_vecs_deg(
    const int* __restrict__ dst,
    const float* __restrict__ lin1, const float* __restrict__ line1,
    const float* __restrict__ as1, const float* __restrict__ ad1,
    const float* __restrict__ ae1,
    const float* __restrict__ lin2, const float* __restrict__ line2,
    const float* __restrict__ as2, const float* __restrict__ ad2,
    const float* __restrict__ ae2,
    float* __restrict__ vS, float* __restrict__ vD, float* __restrict__ vE,
    int* __restrict__ deg, int E)
{
  int b = blockIdx.x, t = threadIdx.x;
  if (b < 6) {
    int l = b / 3, kind = b % 3;
    const float* lin = (kind == 2) ? (l ? line2 : line1) : (l ? lin2 : lin1);
    const float* att = (kind == 0) ? (l ? as2 : as1)
                     : (kind == 1) ? (l ? ad2 : ad1) : (l ? ae2 : ae1);
    float* out = ((kind == 0) ? vS : (kind == 1) ? vD : vE) + l * 256;
    int c = t >> 2, hd = t & 3;
    float acc = 0.f;
    for (int cc = 0; cc < CHC; cc++)
      acc += lin[c * (HEADS * CHC) + hd * CHC + cc] * att[hd * CHC + cc];
    out[c * 4 + hd] = acc;
  }
  int e = b * 256 + t;
  if (e < E) atomicAdd(&deg[dst[e]], 1);
}

// ---- scan kernels: per-block scan + fused block-offset apply ----
__global__ __launch_bounds__(1024) void k_scan1(const int* __restrict__ deg,
    int* __restrict__ rowptr, int* __restrict__ bsum, int n)
{
  __shared__ int wsum[16];
  int t = threadIdx.x, wv = t >> 6, lane = t & 63;
  int i = blockIdx.x * 1024 + t;
  int val = (i < n) ? deg[i] : 0;
  int sc = val;
  #pragma unroll
  for (int off = 1; off < 64; off <<= 1) {
    int u = __shfl_up(sc, off);
    if (lane >= off) sc += u;
  }
  if (lane == 63) wsum[wv] = sc;
  __syncthreads();
  int woff = 0;
  #pragma unroll
  for (int k = 0; k < 16; k++) woff += (k < wv) ? wsum[k] : 0;
  if (i < n) rowptr[i] = woff + sc - val;
  if (t == 0) {
    int tot = 0;
    #pragma unroll
    for (int k = 0; k < 16; k++) tot += wsum[k];
    bsum[blockIdx.x] = tot;
  }
}

// apply block offsets + copy rowptr->cnt + rowptr[n]
__global__ __launch_bounds__(1024) void k_scan23(const int* __restrict__ bsum,
    int* __restrict__ rowptr, int* __restrict__ cnt, int nb, int n)
{
  int b = blockIdx.x;
  int t = threadIdx.x;
  int off = 0;
  for (int j = 0; j < b; j++) off += bsum[j];
  int i = b * 1024 + t;
  if (i < n) {
    int rv = rowptr[i] + off;
    rowptr[i] = rv;
    cnt[i] = rv;
  }
  if (b == 0 && t == 0) {
    int tot = 0;
    for (int j = 0; j < nb; j++) tot += bsum[j];
    rowptr[n] = tot;
  }
}

// CSR fill + edge a_edge fused (no perm array). Lane-owns-edge.
__global__ __launch_bounds__(256) void k_fill_aeg(const int* __restrict__ src,
    const int* __restrict__ dst, const float* __restrict__ eattr,
    const float* __restrict__ we, const float* __restrict__ be,
    const float* __restrict__ vE, int* __restrict__ cnt,
    int* __restrict__ eid, int* __restrict__ srcs,
    float* __restrict__ aeg1, float* __restrict__ aeg2, int E)
{
  __shared__ float4 we_t4[HID][4];
  __shared__ float4 vE_s[2][HID];
  __shared__ float  be_s[HID];
  int t = threadIdx.x;
  for (int i = t; i < FE * HID; i += 256) {
    int k = i >> 6, c = i & 63;
    ((float*)we_t4)[c * 16 + k] = we[i];
  }
  for (int i = t; i < 512; i += 256) ((float*)vE_s)[i] = vE[i];
  if (t < HID) be_s[t] = be[t];
  __syncthreads();

  int e = blockIdx.x * 256 + t;
  if (e >= E) return;
  int d = dst[e];
  int pos = atomicAdd(&cnt[d], 1);
  eid[pos] = e;
  srcs[pos] = src[e];
  const float4* er = (const float4*)(eattr + (size_t)e * FE);
  float4 A = er[0], B = er[1], C4 = er[2], D = er[3];
  float ta[FE] = {A.x, A.y, A.z, A.w, B.x, B.y, B.z, B.w,
                  C4.x, C4.y, C4.z, C4.w, D.x, D.y, D.z, D.w};
  float4 acc1 = make_float4(0.f, 0.f, 0.f, 0.f);
  float4 acc2 = make_float4(0.f, 0.f, 0.f, 0.f);
  #pragma unroll 4
  for (int c = 0; c < HID; c++) {
    float4 w0 = we_t4[c][0], w1 = we_t4[c][1], w2 = we_t4[c][2], w3 = we_t4[c][3];
    float ea = be_s[c];
    ea += ta[0] * w0.x + ta[1] * w0.y + ta[2] * w0.z + ta[3] * w0.w;
    ea += ta[4] * w1.x + ta[5] * w1.y + ta[6] * w1.z + ta[7] * w1.w;
    ea += ta[8] * w2.x + ta[9] * w2.y + ta[10] * w2.z + ta[11] * w2.w;
    ea += ta[12] * w3.x + ta[13] * w3.y + ta[14] * w3.z + ta[15] * w3.w;
    ea = fmaxf(ea, 0.f);
    float4 u1 = vE_s[0][c], u2 = vE_s[1][c];
    acc1.x += ea * u1.x; acc1.y += ea * u1.y; acc1.z += ea * u1.z; acc1.w += ea * u1.w;
    acc2.x += ea * u2.x; acc2.y += ea * u2.y; acc2.z += ea * u2.z; acc2.w += ea * u2.w;
  }
  *(float4*)(aeg1 + (size_t)pos * 4) = acc1;
  *(float4*)(aeg2 + (size_t)pos * 4) = acc2;
}

// self-loop a_edge = segment-mean of CSR aeg values (slot E+v)
__global__ __launch_bounds__(256) void k_self_aeg(const int* __restrict__ rowptr,
    float* __restrict__ aeg1, float* __restrict__ aeg2, int E, int n)
{
  int t = threadIdx.x;
  int v = blockIdx.x * 32 + (t >> 3);
  if (v >= n) return;
  int ent = t & 7;
  int h = ent & 3;
  const float* srcp = (ent < 4) ? aeg1 : aeg2;
  int r0 = rowptr[v], r1 = rowptr[v + 1];
  float s = 0.f;
  for (int j = r0; j < r1; j++) s += srcp[(size_t)j * 4 + h];
  float m = s / fmaxf((float)(r1 - r0), 1.f);
  if (ent < 4) aeg1[((size_t)E + v) * 4 + h] = m;
  else         aeg2[((size_t)E + v) * 4 + h] = m;
}

// Fused layer-1 front-end: x1 = relu(x@wn+bn) (LDS only) + att dots +
// h(bf16) = x1 @ lin. 16 nodes/block.
__global__ __launch_bounds__(256) void k_hx1(const float* __restrict__ x,
    const float* __restrict__ wn, const float* __restrict__ bn,
    const float* __restrict__ vS, const float* __restrict__ vD,
    const float* __restrict__ lin, unsigned short* __restrict__ h_bf,
    float* __restrict__ ssrc, float* __restrict__ sdst, int n)
{
  int t = threadIdx.x, wv = t >> 6, lane = t & 63;
  int v0 = blockIdx.x * 16;
  __shared__ float xin_s[16][FN];
  __shared__ float xs[16][HID];
  if (t < 128) {
    int node = t >> 3, c4 = (t & 7) * 4;
    int vv = v0 + node;
    float4 val = make_float4(0.f, 0.f, 0.f, 0.f);
    if (vv < n) val = *(const float4*)(x + (size_t)vv * FN + c4);
    *(float4*)&xin_s[node][c4] = val;
  }
  __syncthreads();
  {
    int nd = t >> 4, cg_ = t & 15;
    int vv = v0 + nd;
    const float4* wn4 = (const float4*)wn;
    float4 a = ((const float4*)bn)[cg_];
    #pragma unroll 8
    for (int k = 0; k < FN; k++) {
      float xv = xin_s[nd][k];
      float4 w = wn4[k * 16 + cg_];
      a.x += xv * w.x; a.y += xv * w.y; a.z += xv * w.z; a.w += xv * w.w;
    }
    a.x = fmaxf(a.x, 0.f); a.y = fmaxf(a.y, 0.f);
    a.z = fmaxf(a.z, 0.f); a.w = fmaxf(a.w, 0.f);
    *(float4*)&xs[nd][cg_ * 4] = a;
    const float4* vS4 = (const float4*)vS;
    const float4* vD4 = (const float4*)vD;
    int c0 = cg_ * 4;
    float4 vs0 = vS4[c0], vs1 = vS4[c0 + 1], vs2 = vS4[c0 + 2], vs3 = vS4[c0 + 3];
    float4 vd0 = vD4[c0], vd1 = vD4[c0 + 1], vd2 = vD4[c0 + 2], vd3 = vD4[c0 + 3];
    float pS[4], pD[4];
    pS[0] = a.x * vs0.x + a.y * vs1.x + a.z * vs2.x + a.w * vs3.x;
    pS[1] = a.x * vs0.y + a.y * vs1.y + a.z * vs2.y + a.w * vs3.y;
    pS[2] = a.x * vs0.z + a.y * vs1.z + a.z * vs2.z + a.w * vs3.z;
    pS[3] = a.x * vs0.w + a.y * vs1.w + a.z * vs2.w + a.w * vs3.w;
    pD[0] = a.x * vd0.x + a.y * vd1.x + a.z * vd2.x + a.w * vd3.x;
    pD[1] = a.x * vd0.y + a.y * vd1.y + a.z * vd2.y + a.w * vd3.y;
    pD[2] = a.x * vd0.z + a.y * vd1.z + a.z * vd2.z + a.w * vd3.z;
    pD[3] = a.x * vd0.w + a.y * vd1.w + a.z * vd2.w + a.w * vd3.w;
    #pragma unroll
    for (int off = 1; off < 16; off <<= 1) {
      #pragma unroll
      for (int h = 0; h < 4; h++) {
        pS[h] += __shfl_xor(pS[h], off);
        pD[h] += __shfl_xor(pD[h], off);
      }
    }
    if (cg_ == 0 && vv < n) {
      *(float4*)(ssrc + (size_t)vv * 4) = make_float4(pS[0], pS[1], pS[2], pS[3]);
      *(float4*)(sdst + (size_t)vv * 4) = make_float4(pD[0], pD[1], pD[2], pD[3]);
    }
  }
  __syncthreads();
  float acc[4][4];
  #pragma unroll
  for (int i = 0; i < 4; i++)
    #pragma unroll
    for (int j = 0; j < 4; j++) acc[i][j] = 0.f;
  const float4* lin4 = (const float4*)lin;
  int nd0 = wv * 4;
  #pragma unroll 4
  for (int kb = 0; kb < 16; kb++) {
    float4 xv[4];
    #pragma unroll
    for (int i = 0; i < 4; i++) xv[i] = *(const float4*)&xs[nd0 + i][kb * 4];
    float4 lv0 = lin4[(kb * 4 + 0) * 64 + lane];
    float4 lv1 = lin4[(kb * 4 + 1) * 64 + lane];
    float4 lv2 = lin4[(kb * 4 + 2) * 64 + lane];
    float4 lv3 = lin4[(kb * 4 + 3) * 64 + lane];
    #pragma unroll
    for (int i = 0; i < 4; i++) {
      acc[i][0] += xv[i].x * lv0.x + xv[i].y * lv1.x + xv[i].z * lv2.x + xv[i].w * lv3.x;
      acc[i][1] += xv[i].x * lv0.y + xv[i].y * lv1.y + xv[i].z * lv2.y + xv[i].w * lv3.y;
      acc[i][2] += xv[i].x * lv0.z + xv[i].y * lv1.z + xv[i].z * lv2.z + xv[i].w * lv3.z;
      acc[i][3] += xv[i].x * lv0.w + xv[i].y * lv1.w + xv[i].z * lv2.w + xv[i].w * lv3.w;
    }
  }
  #pragma unroll
  for (int i = 0; i < 4; i++) {
    int v = v0 + nd0 + i;
    if (v < n) {
      uint2 u;
      u.x = pack2bf(acc[i][0], acc[i][1]);
      u.y = pack2bf(acc[i][2], acc[i][3]);
      *(uint2*)(h_bf + (size_t)v * 256 + lane * 4) = u;
    }
  }
}

// h(bf16) = x @ lin [n,256]. 16 nodes/block; thread = 4 nodes x 4 channels.
__global__ __launch_bounds__(256) void k_h(const float* __restrict__ xin,
    const float* __restrict__ lin, unsigned short* __restrict__ h_bf, int n)
{
  int t = threadIdx.x, wv = t >> 6, lane = t & 63;
  int v0 = blockIdx.x * 16;
  __shared__ float xs[16][HID];
  {
    int node = t >> 4, ch4 = (t & 15) * 4;
    int vv = v0 + node;
    float4 val = make_float4(0.f, 0.f, 0.f, 0.f);
    if (vv < n) val = *(const float4*)(xin + (size_t)vv * HID + ch4);
    *(float4*)&xs[node][ch4] = val;
  }
  __syncthreads();
  float acc[4][4];
  #pragma unroll
  for (int i = 0; i < 4; i++)
    #pragma unroll
    for (int j = 0; j < 4; j++) acc[i][j] = 0.f;
  const float4* lin4 = (const float4*)lin;
  int nd0 = wv * 4;
  #pragma unroll 4
  for (int kb = 0; kb < 16; kb++) {
    float4 xv[4];
    #pragma unroll
    for (int i = 0; i < 4; i++) xv[i] = *(const float4*)&xs[nd0 + i][kb * 4];
    float4 lv0 = lin4[(kb * 4 + 0) * 64 + lane];
    float4 lv1 = lin4[(kb * 4 + 1) * 64 + lane];
    float4 lv2 = lin4[(kb * 4 + 2) * 64 + lane];
    float4 lv3 = lin4[(kb * 4 + 3) * 64 + lane];
    #pragma unroll
    for (int i = 0; i < 4; i++) {
      acc[i][0] += xv[i].x * lv0.x + xv[i].y * lv1.x + xv[i].z * lv2.x + xv[i].w * lv3.x;
      acc[i][1] += xv[i].x * lv0.y + xv[i].y * lv1.y + xv[i].z * lv2.y + xv[i].w * lv3.y;
      acc[i][2] += xv[i].x * lv0.z + xv[i].y * lv1.z + xv[i].z * lv2.z + xv[i].w * lv3.z;
      acc[i][3] += xv[i].x * lv0.w + xv[i].y * lv1.w + xv[i].z * lv2.w + xv[i].w * lv3.w;
    }
  }
  #pragma unroll
  for (int i = 0; i < 4; i++) {
    int v = v0 + nd0 + i;
    if (v < n) {
      uint2 u;
      u.x = pack2bf(acc[i][0], acc[i][1]);
      u.y = pack2bf(acc[i][2], acc[i][3]);
      *(uint2*)(h_bf + (size_t)v * 256 + lane * 4) = u;
    }
  }
}

// Fused per-node: softmax + alpha + aggregation + head-mean + bias + leaky +
// LayerNorm (+ optional fused next-layer att dots). WAVE per node.
// R7-best structure (measured 46.6 us).
template<bool DOTS>
__global__ __launch_bounds__(256) void k_node(
    const unsigned short* __restrict__ h_bf, const float* __restrict__ ssrc,
    const float* __restrict__ sdst, const float* __restrict__ aegc,
    const int* __restrict__ rowptr, const int* __restrict__ eidArr,
    const int* __restrict__ srcs, const float* __restrict__ bias,
    const float* __restrict__ gamma, const float* __restrict__ beta,
    const float* __restrict__ vS2, const float* __restrict__ vD2,
    float* __restrict__ alpha_out, float* __restrict__ xout,
    float* __restrict__ ssrc_o, float* __restrict__ sdst_o, int n, int E)
{
  __shared__ float als[4][64][4];   // per-wave alpha exchange (conflict-free)
  int t = threadIdx.x; int wv = t >> 6, lane = t & 63;
  int v = blockIdx.x * 4 + wv;
  if (v >= n) return;
  int r0 = rowptr[v], r1 = rowptr[v + 1];
  int deg = r1 - r0, ne = deg + 1;      // + self loop (edge id E+v, src v)
  int coff = lane * 4;                  // aggregation: 4 channels per lane
  int hh = lane >> 4;                   // head owning those channels
  float acc0 = 0.f, acc1 = 0.f, acc2 = 0.f, acc3 = 0.f;
  const float4* aeg4 = (const float4*)aegc;
  const float4* ss4p = (const float4*)ssrc;
  float4 sd4 = ((const float4*)sdst)[v];

  if (ne <= 64) {
    int s = v, eo = E + v;
    if (lane < deg) { s = srcs[r0 + lane]; eo = eidArr[r0 + lane]; }
    bool valid = (lane < ne);
    float a0 = -INFINITY, a1 = -INFINITY, a2 = -INFINITY, a3 = -INFINITY;
    if (valid) {
      float4 ae4 = aeg4[(lane < deg) ? (r0 + lane) : (E + v)];
      float4 ss4 = ss4p[s];
      a0 = ss4.x + sd4.x + ae4.x; a0 = (a0 > 0.f) ? a0 : 0.2f * a0;
      a1 = ss4.y + sd4.y + ae4.y; a1 = (a1 > 0.f) ? a1 : 0.2f * a1;
      a2 = ss4.z + sd4.z + ae4.z; a2 = (a2 > 0.f) ? a2 : 0.2f * a2;
      a3 = ss4.w + sd4.w + ae4.w; a3 = (a3 > 0.f) ? a3 : 0.2f * a3;
    }
    float m0, m1, m2, m3;
    {
      bool hi0 = lane & 1;
      float k0 = hi0 ? a2 : a0, s0 = hi0 ? a0 : a2;
      float k1 = hi0 ? a3 : a1, s1 = hi0 ? a1 : a3;
      float q0 = fmaxf(k0, __shfl_xor(s0, 1));
      float q1 = fmaxf(k1, __shfl_xor(s1, 1));
      bool hi1 = lane & 2;
      float k2 = hi1 ? q1 : q0, s2 = hi1 ? q0 : q1;
      float r = fmaxf(k2, __shfl_xor(s2, 2));
      r = fmaxf(r, __shfl_xor(r, 4));
      r = fmaxf(r, __shfl_xor(r, 8));
      r = fmaxf(r, __shfl_xor(r, 16));
      r = fmaxf(r, __shfl_xor(r, 32));
      m0 = __shfl(r, 0); m1 = __shfl(r, 2); m2 = __shfl(r, 1); m3 = __shfl(r, 3);
    }
    float e0 = __expf(a0 - m0), e1 = __expf(a1 - m1);
    float e2 = __expf(a2 - m2), e3 = __expf(a3 - m3);
    float d0, d1, d2, d3;
    {
      bool hi0 = lane & 1;
      float k0 = hi0 ? e2 : e0, s0 = hi0 ? e0 : e2;
      float k1 = hi0 ? e3 : e1, s1 = hi0 ? e1 : e3;
      float q0 = k0 + __shfl_xor(s0, 1);
      float q1 = k1 + __shfl_xor(s1, 1);
      bool hi1 = lane & 2;
      float k2 = hi1 ? q1 : q0, s2 = hi1 ? q0 : q1;
      float r = k2 + __shfl_xor(s2, 2);
      r += __shfl_xor(r, 4);
      r += __shfl_xor(r, 8);
      r += __shfl_xor(r, 16);
      r += __shfl_xor(r, 32);
      d0 = __shfl(r, 0); d1 = __shfl(r, 2); d2 = __shfl(r, 1); d3 = __shfl(r, 3);
    }
    float4 alf = make_float4(e0 / d0, e1 / d1, e2 / d2, e3 / d3);
    if (valid) {
      f32x4 alv = {alf.x, alf.y, alf.z, alf.w};
      __builtin_nontemporal_store(alv, (f32x4*)alpha_out + eo);
    }
    *(float4*)als[wv][lane] = alf;
    __builtin_amdgcn_wave_barrier();
    __builtin_amdgcn_sched_barrier(0);
    int jj = 0;
    for (; jj + 3 < ne; jj += 4) {
      int s0 = __shfl(s, jj), s1 = __shfl(s, jj + 1);
      int s2 = __shfl(s, jj + 2), s3 = __shfl(s, jj + 3);
      float al0 = als[wv][jj][hh],     al1 = als[wv][jj + 1][hh];
      float al2 = als[wv][jj + 2][hh], al3 = als[wv][jj + 3][hh];
      uint2 u0 = *(const uint2*)(h_bf + (size_t)s0 * 256 + coff);
      uint2 u1 = *(const uint2*)(h_bf + (size_t)s1 * 256 + coff);
      uint2 u2 = *(const uint2*)(h_bf + (size_t)s2 * 256 + coff);
      uint2 u3 = *(const uint2*)(h_bf + (size_t)s3 * 256 + coff);
      acc0 += al0 * bf2f((unsigned short)(u0.x & 0xffff))
            + al1 * bf2f((unsigned short)(u1.x & 0xffff))
            + al2 * bf2f((unsigned short)(u2.x & 0xffff))
            + al3 * bf2f((unsigned short)(u3.x & 0xffff));
      acc1 += al0 * bf2f((unsigned short)(u0.x >> 16))
            + al1 * bf2f((unsigned short)(u1.x >> 16))
            + al2 * bf2f((unsigned short)(u2.x >> 16))
            + al3 * bf2f((unsigned short)(u3.x >> 16));
      acc2 += al0 * bf2f((unsigned short)(u0.y & 0xffff))
            + al1 * bf2f((unsigned short)(u1.y & 0xffff))
            + al2 * bf2f((unsigned short)(u2.y & 0xffff))
            + al3 * bf2f((unsigned short)(u3.y & 0xffff));
      acc3 += al0 * bf2f((unsigned short)(u0.y >> 16))
            + al1 * bf2f((unsigned short)(u1.y >> 16))
            + al2 * bf2f((unsigned short)(u2.y >> 16))
            + al3 * bf2f((unsigned short)(u3.y >> 16));
    }
    for (; jj < ne; jj++) {
      int s0 = __shfl(s, jj);
      float al0 = als[wv][jj][hh];
      uint2 u0 = *(const uint2*)(h_bf + (size_t)s0 * 256 + coff);
      acc0 += al0 * bf2f((unsigned short)(u0.x & 0xffff));
      acc1 += al0 * bf2f((unsigned short)(u0.x >> 16));
      acc2 += al0 * bf2f((unsigned short)(u0.y & 0xffff));
      acc3 += al0 * bf2f((unsigned short)(u0.y >> 16));
    }
  } else {
    // ---- chunked two-pass fallback (deg > 63, rare) ----
    int j4 = lane >> 2, hb = lane & 3;
    float sd = sdst[v * 4 + hb];
    float m = -INFINITY;
    for (int jb = 0; jb < ne; jb += 16) {
      int jc = jb + j4;
      if (jc < ne) {
        int s2 = (jc < deg) ? srcs[r0 + jc] : v;
        float ae = (jc < deg) ? aegc[(size_t)(r0 + jc) * 4 + hb]
                              : aegc[((size_t)E + v) * 4 + hb];
        float a = ssrc[s2 * 4 + hb] + sd + ae;
        a = (a > 0.f) ? a : 0.2f * a;
        m = fmaxf(m, a);
      }
    }
    m = fmaxf(m, __shfl_xor(m, 4));
    m = fmaxf(m, __shfl_xor(m, 8));
    m = fmaxf(m, __shfl_xor(m, 16));
    m = fmaxf(m, __shfl_xor(m, 32));
    float den = 0.f;
    for (int jb = 0; jb < ne; jb += 16) {
      int jc = jb + j4;
      if (jc < ne) {
        int s2 = (jc < deg) ? srcs[r0 + jc] : v;
        float ae = (jc < deg) ? aegc[(size_t)(r0 + jc) * 4 + hb]
                              : aegc[((size_t)E + v) * 4 + hb];
        float a = ssrc[s2 * 4 + hb] + sd + ae;
        a = (a > 0.f) ? a : 0.2f * a;
        den += __expf(a - m);
      }
    }
    den += __shfl_xor(den, 4);
    den += __shfl_xor(den, 8);
    den += __shfl_xor(den, 16);
    den += __shfl_xor(den, 32);
    float rden = 1.f / den;
    for (int jb = 0; jb < ne; jb += 16) {
      int jc = jb + j4;
      if (jc < ne) {
        int s2 = (jc < deg) ? srcs[r0 + jc] : v;
        int eo = (jc < deg) ? eidArr[r0 + jc] : E + v;
        float ae = (jc < deg) ? aegc[(size_t)(r0 + jc) * 4 + hb]
                              : aegc[((size_t)E + v) * 4 + hb];
        float a = ssrc[s2 * 4 + hb] + sd + ae;
        a = (a > 0.f) ? a : 0.2f * a;
        alpha_out[(size_t)eo * 4 + hb] = __expf(a - m) * rden;
      }
    }
    float sdh = __shfl(sd, hh);
    float mh  = __shfl(m, hh);
    float rdh = __shfl(rden, hh);
    for (int jc = 0; jc < ne; jc++) {
      int s0 = (jc < deg) ? srcs[r0 + jc] : v;
      size_t ap = (jc < deg) ? (size_t)(r0 + jc) : (size_t)E + v;
      float a = ssrc[s0 * 4 + hh] + sdh + aegc[ap * 4 + hh];
      a = (a > 0.f) ? a : 0.2f * a;
      float al = __expf(a - mh) * rdh;
      uint2 u = *(const uint2*)(h_bf + (size_t)s0 * 256 + coff);
      acc0 += al * bf2f((unsigned short)(u.x & 0xffff));
      acc1 += al * bf2f((unsigned short)(u.x >> 16));
      acc2 += al * bf2f((unsigned short)(u.y & 0xffff));
      acc3 += al * bf2f((unsigned short)(u.y >> 16));
    }
  }

  // ---- head reduce: lanes {L, L+16, L+32, L+48} hold heads 0..3 ----
  acc0 += __shfl_xor(acc0, 16); acc0 += __shfl_xor(acc0, 32);
  acc1 += __shfl_xor(acc1, 16); acc1 += __shfl_xor(acc1, 32);
  acc2 += __shfl_xor(acc2, 16); acc2 += __shfl_xor(acc2, 32);
  acc3 += __shfl_xor(acc3, 16); acc3 += __shfl_xor(acc3, 32);

  // ---- epilogue: bias + leaky(0.01) + LayerNorm(64); all lanes hold copy ----
  int c16 = lane & 15;
  float4 b4 = ((const float4*)bias)[c16];
  float v0 = acc0 * 0.25f + b4.x;
  float v1 = acc1 * 0.25f + b4.y;
  float v2 = acc2 * 0.25f + b4.z;
  float v3 = acc3 * 0.25f + b4.w;
  v0 = (v0 > 0.f) ? v0 : 0.01f * v0;
  v1 = (v1 > 0.f) ? v1 : 0.01f * v1;
  v2 = (v2 > 0.f) ? v2 : 0.01f * v2;
  v3 = (v3 > 0.f) ? v3 : 0.01f * v3;
  float mu = v0 + v1 + v2 + v3;
  mu += __shfl_xor(mu, 1); mu += __shfl_xor(mu, 2);
  mu += __shfl_xor(mu, 4); mu += __shfl_xor(mu, 8);
  mu *= (1.f / 64.f);
  float d0 = v0 - mu, d1 = v1 - mu, d2 = v2 - mu, d3 = v3 - mu;
  float var = d0 * d0 + d1 * d1 + d2 * d2 + d3 * d3;
  var += __shfl_xor(var, 1); var += __shfl_xor(var, 2);
  var += __shfl_xor(var, 4); var += __shfl_xor(var, 8);
  var *= (1.f / 64.f);
  float rstd = rsqrtf(var + 1e-5f);
  float4 g4 = ((const float4*)gamma)[c16];
  float4 be4 = ((const float4*)beta)[c16];
  float y0 = d0 * rstd * g4.x + be4.x;
  float y1 = d1 * rstd * g4.y + be4.y;
  float y2 = d2 * rstd * g4.z + be4.z;
  float y3 = d3 * rstd * g4.w + be4.w;
  if (lane < 16) {
    float4 y = make_float4(y0, y1, y2, y3);
    *(float4*)(xout + (size_t)v * HID + lane * 4) = y;
  }
  if constexpr (DOTS) {
    // next-layer att dots: p_h = y . vS2[:,h]; 16-lane reduce = ONE full copy
    int c0 = c16 * 4;
    float4 vs0 = ((const float4*)vS2)[c0],     vs1 = ((const float4*)vS2)[c0 + 1];
    float4 vs2 = ((const float4*)vS2)[c0 + 2], vs3 = ((const float4*)vS2)[c0 + 3];
    float4 vd0 = ((const float4*)vD2)[c0],     vd1 = ((const float4*)vD2)[c0 + 1];
    float4 vd2 = ((const float4*)vD2)[c0 + 2], vd3 = ((const float4*)vD2)[c0 + 3];
    float pS[4], pD[4];
    pS[0] = y0 * vs0.x + y1 * vs1.x + y2 * vs2.x + y3 * vs3.x;
    pS[1] = y0 * vs0.y + y1 * vs1.y + y2 * vs2.y + y3 * vs3.y;
    pS[2] = y0 * vs0.z + y1 * vs1.z + y2 * vs2.z + y3 * vs3.z;
    pS[3] = y0 * vs0.w + y1 * vs1.w + y2 * vs2.w + y3 * vs3.w;
    pD[0] = y0 * vd0.x + y1 * vd1.x + y2 * vd2.x + y3 * vd3.x;
    pD[1] = y0 * vd0.y + y1 * vd1.y + y2 * vd2.y + y3 * vd3.y;
    pD[2] = y0 * vd0.z + y1 * vd1.z + y2 * vd2.z + y3 * vd3.z;
    pD[3] = y0 * vd0.w + y1 * vd1.w + y2 * vd2.w + y3 * vd3.w;
    #pragma unroll
    for (int off = 1; off < 16; off <<= 1) {
      #pragma unroll
      for (int h = 0; h < 4; h++) {
        pS[h] += __shfl_xor(pS[h], off);
        pD[h] += __shfl_xor(pD[h], off);
      }
    }
    if (lane == 0) {
      *(float4*)(ssrc_o + (size_t)v * 4) = make_float4(pS[0], pS[1], pS[2], pS[3]);
      *(float4*)(sdst_o + (size_t)v * 4) = make_float4(pD[0], pD[1], pD[2], pD[3]);
    }
  }
}

extern "C" void kernel_launch(void* const* d_in, const int* in_sizes, int n_in,
                              void* d_out, int out_size, void* d_ws, size_t ws_size,
                              hipStream_t stream)
{
  const float* x     = (const float*)d_in[0];
  const int*   eidx  = (const int*)d_in[1];
  const float* eattr = (const float*)d_in[2];
  const float* wn    = (const float*)d_in[3];
  const float* bn    = (const float*)d_in[4];
  const float* we    = (const float*)d_in[5];
  const float* be    = (const float*)d_in[6];
  const float* lin1  = (const float*)d_in[7];
  const float* line1 = (const float*)d_in[8];
  const float* as1   = (const float*)d_in[9];
  const float* ad1   = (const float*)d_in[10];
  const float* ae1   = (const float*)d_in[11];
  const float* b1    = (const float*)d_in[12];
  const float* g1    = (const float*)d_in[13];
  const float* bt1   = (const float*)d_in[14];
  const float* lin2  = (const float*)d_in[15];
  const float* line2 = (const float*)d_in[16];
  const float* as2   = (const float*)d_in[17];
  const float* ad2   = (const float*)d_in[18];
  const float* ae2   = (const float*)d_in[19];
  const float* b2    = (const float*)d_in[20];
  const float* g2    = (const float*)d_in[21];
  const float* bt2   = (const float*)d_in[22];

  int n = in_sizes[0] / FN;
  int E = in_sizes[1] / 2;
  const int* srcA = eidx;
  const int* dstA = eidx + E;

  float* out_h2 = (float*)d_out;
  float* alpha1 = out_h2 + (size_t)n * HID;
  float* alpha2 = alpha1 + (size_t)(E + n) * 4;

  char* ws = (char*)d_ws;
  size_t off = 0;
  auto alloc = [&](size_t bytes) -> char* {
    char* p = ws + off;
    off += (bytes + 255) & ~(size_t)255;
    return p;
  };
  unsigned short* h_bf = (unsigned short*)alloc((size_t)n * 256 * 2);
  float* h1      = (float*)alloc((size_t)n * HID * 4);
  float* aeg1c   = (float*)alloc((size_t)(E + n) * 4 * 4);
  float* aeg2c   = (float*)alloc((size_t)(E + n) * 4 * 4);
  float* ssrc1   = (float*)alloc((size_t)n * 4 * 4);
  float* sdst1   = (float*)alloc((size_t)n * 4 * 4);
  float* ssrc2   = (float*)alloc((size_t)n * 4 * 4);
  float* sdst2   = (float*)alloc((size_t)n * 4 * 4);
  float* vS      = (float*)alloc(512 * 4);
  float* vD      = (float*)alloc(512 * 4);
  float* vE      = (float*)alloc(512 * 4);
  int*   deg     = (int*)alloc((size_t)n * 4);
  int*   cnt     = (int*)alloc((size_t)n * 4);
  int*   rowptr  = (int*)alloc((size_t)(n + 1) * 4);
  int*   eid     = (int*)alloc((size_t)E * 4);
  int*   srcs    = (int*)alloc((size_t)E * 4);
  int*   bsum    = (int*)alloc(1024 * 4);

  hipMemsetAsync(deg, 0, (size_t)n * 4, stream);

  int nb = (n + 1023) / 1024;
  k_vecs_deg<<<(E + 255) / 256, 256, 0, stream>>>(dstA,
      lin1, line1, as1, ad1, ae1, lin2, line2, as2, ad2, ae2,
      vS, vD, vE, deg, E);
  k_scan1<<<nb, 1024, 0, stream>>>(deg, rowptr, bsum, n);
  k_scan23<<<nb, 1024, 0, stream>>>(bsum, rowptr, cnt, nb, n);
  k_fill_aeg<<<(E + 255) / 256, 256, 0, stream>>>(srcA, dstA, eattr, we, be,
      vE, cnt, eid, srcs, aeg1c, aeg2c, E);
  k_self_aeg<<<(n + 31) / 32, 256, 0, stream>>>(rowptr, aeg1c, aeg2c, E, n);

  // layer 1 (x1 GEMM + att dots fused into the h GEMM)
  k_hx1<<<(n + 15) / 16, 256, 0, stream>>>(x, wn, bn, vS, vD, lin1, h_bf,
                                           ssrc1, sdst1, n);
  k_node<true><<<(n + 3) / 4, 256, 0, stream>>>(h_bf, ssrc1, sdst1, aeg1c,
      rowptr, eid, srcs, b1, g1, bt1, vS + 256, vD + 256,
      alpha1, h1, ssrc2, sdst2, n, E);
  // layer 2
  k_h<<<(n + 15) / 16, 256, 0, stream>>>(h1, lin2, h_bf, n);
  k_node<false><<<(n + 3) / 4, 256, 0, stream>>>(h_bf, ssrc2, sdst2, aeg2c,
      rowptr, eid, srcs, b2, g2, bt2, nullptr, nullptr,
      alpha2, out_h2, nullptr, nullptr, n, E);
}